// Round 1
// baseline (2996.499 us; speedup 1.0000x reference)
//
#include <hip/hip_runtime.h>
#include <hip/hip_bf16.h>
#include <cstdint>

// Problem constants
// B=8, N=8192, S=1024 (npoint), C=64 features
// branch0: radius 0.4, K=32, layers 64x67, 64x64, 128x64
// branch1: radius 0.8, K=64, layers 64x67, 128x64, 256x128

// ---------------- workspace layout (bytes) ----------------
static const size_t OFF_WT    = 0;          // transposed weights: 61824 floats (247 KB)
static const size_t OFF_STATS = 262144;     // 704 ch * 128 slots * 2 * 4B
static const size_t STATS_BYTES = 720896;
static const size_t OFF_AFF   = 1048576;    // per-layer scale/shift: 1408 floats
static const size_t OFF_PTS   = 1114112;    // FPS pts SoA: 8 * 3 * 8200 floats
static const size_t OFF_IDX0  = 2097152;    // 8*1024*32 ints (1 MB)
static const size_t OFF_IDX1  = 3145728;    // 8*1024*64 ints (2 MB)
static const size_t OFF_MX    = 5242880;    // 256*8192 fp32 (8 MB)
static const size_t OFF_MN    = 13631488;   // 8 MB
static const size_t OFF_Y0    = 22020096;   // bf16, 64ch * 524288 (64 MB)
static const size_t OFF_Y1    = 90177536;   // bf16, 128ch * 524288 (128 MB); end ~224.4 MB

// ---------------- weight transpose: w[M][K] -> wt[K][M] ----------------
__global__ void prep_weights(const float* __restrict__ w0, const float* __restrict__ w1,
                             const float* __restrict__ w2, const float* __restrict__ w3,
                             const float* __restrict__ w4, const float* __restrict__ w5,
                             float* __restrict__ wt) {
    int id = blockIdx.x * 256 + threadIdx.x;
    const int sz[6] = {4288, 4096, 8192, 4288, 8192, 32768};
    const int Ms[6] = {64, 64, 128, 64, 128, 256};
    const int Ks[6] = {67, 64, 64, 67, 64, 128};
    const float* wp[6] = {w0, w1, w2, w3, w4, w5};
    int off = 0;
    for (int l = 0; l < 6; ++l) {
        if (id < off + sz[l]) {
            int e = id - off;
            int K = Ks[l], M = Ms[l];
            int m = e / K, i = e - m * K;
            wt[off + i * M + m] = wp[l][e];
            return;
        }
        off += sz[l];
    }
}

// ---------------- FPS: one block per batch ----------------
// pts[0] = mean(xyz), pts[1+i] = xyz[i]; 1024 iterations of (dist update, argmax).
// Thread t owns pts indices p = t + j*1024 (j=0..8). Packed-u64 shuffle argmax,
// tie-break = smallest index (matches jnp.argmax first-occurrence).
__global__ __launch_bounds__(1024) void fps_kernel(const float* __restrict__ xyz,
                                                   float* __restrict__ newxyz,
                                                   float* __restrict__ ptsbuf) {
    const int b = blockIdx.x;
    const int t = threadIdx.x;
    const int lane = t & 63, wv = t >> 6;
    const float* xb = xyz + (size_t)b * 8192 * 3;
    float* ptsx = ptsbuf + (size_t)b * 3 * 8200;
    float* ptsy = ptsx + 8200;
    float* ptsz = ptsy + 8200;

    float px[9], py[9], pz[9], d[9];
    float sx = 0.f, sy = 0.f, sz = 0.f;
#pragma unroll
    for (int j = 0; j < 9; ++j) {
        int p = t + j * 1024;
        bool valid = (p <= 8192);
        float x = 0.f, y = 0.f, z = 0.f;
        if (valid && p >= 1) {
            x = xb[(p - 1) * 3 + 0];
            y = xb[(p - 1) * 3 + 1];
            z = xb[(p - 1) * 3 + 2];
            sx += x; sy += y; sz += z;
        }
        px[j] = x; py[j] = y; pz[j] = z;
        d[j] = valid ? 1e10f : -1e30f;
    }
    // block mean reduce
    __shared__ float ldsM[16][3];
    __shared__ float meanv[3];
#pragma unroll
    for (int off = 32; off; off >>= 1) {
        sx += __shfl_xor(sx, off, 64);
        sy += __shfl_xor(sy, off, 64);
        sz += __shfl_xor(sz, off, 64);
    }
    if (lane == 0) { ldsM[wv][0] = sx; ldsM[wv][1] = sy; ldsM[wv][2] = sz; }
    __syncthreads();
    if (t < 3) {
        float s = 0.f;
        for (int w = 0; w < 16; ++w) s += ldsM[w][t];
        meanv[t] = s * (1.f / 8192.f);
    }
    __syncthreads();
    if (t == 0) { px[0] = meanv[0]; py[0] = meanv[1]; pz[0] = meanv[2]; }
    // materialize pts (for centroid broadcast lookups)
#pragma unroll
    for (int j = 0; j < 9; ++j) {
        int p = t + j * 1024;
        if (p <= 8192) { ptsx[p] = px[j]; ptsy[p] = py[j]; ptsz[p] = pz[j]; }
    }
    __syncthreads();

    __shared__ unsigned long long ldsKey[16];
    __shared__ unsigned long long ldsRes;
    int far = 0;
    for (int it = 0; it < 1024; ++it) {
        float cx = ptsx[far], cy = ptsy[far], cz = ptsz[far];  // uniform broadcast load
        if (t == 0) {
            float* o = newxyz + ((size_t)b * 1024 + it) * 3;
            o[0] = cx; o[1] = cy; o[2] = cz;
        }
        float bv = -1e30f;
        int bi = 0;
#pragma unroll
        for (int j = 0; j < 9; ++j) {
            // no-fma ordering to track the numpy/XLA reference closely
            float dx = __fsub_rn(px[j], cx);
            float dy = __fsub_rn(py[j], cy);
            float dz = __fsub_rn(pz[j], cz);
            float dd = __fadd_rn(__fadd_rn(__fmul_rn(dx, dx), __fmul_rn(dy, dy)), __fmul_rn(dz, dz));
            float nd = fminf(d[j], dd);
            d[j] = nd;
            if (nd > bv) { bv = nd; bi = t + j * 1024; }  // ascending p, strict > => smallest idx on tie
        }
        unsigned long long key =
            ((unsigned long long)__float_as_uint(bv) << 32) | (unsigned)(8192 - bi);
#pragma unroll
        for (int off = 32; off; off >>= 1) {
            unsigned long long o = __shfl_xor(key, off, 64);
            if (o > key) key = o;
        }
        if (lane == 0) ldsKey[wv] = key;
        __syncthreads();
        if (t < 16) {
            unsigned long long k2 = ldsKey[t];
#pragma unroll
            for (int off = 8; off; off >>= 1) {
                unsigned long long o = __shfl_xor(k2, off, 16);
                if (o > k2) k2 = o;
            }
            if (t == 0) ldsRes = k2;
        }
        __syncthreads();
        far = 8192 - (int)(unsigned)(ldsRes & 0xffffffffull);
    }
}

// ---------------- ball query: one wave per query ----------------
__global__ void ball_query_kernel(const float* __restrict__ xyz, const float* __restrict__ newxyz,
                                  int* __restrict__ idxout, float r2, int K) {
    int wid = (blockIdx.x * blockDim.x + threadIdx.x) >> 6;  // query id, 0..8191
    int lane = threadIdx.x & 63;
    int b = wid >> 10;
    const float* q = newxyz + (size_t)wid * 3;
    float qx = q[0], qy = q[1], qz = q[2];
    const float* xb = xyz + (size_t)b * 8192 * 3;
    int* out = idxout + (size_t)wid * K;
    int count = 0;
    int first = 0;
    for (int base = 0; base < 8192 && count < K; base += 64) {
        int j = base + lane;
        float dx = __fsub_rn(xb[j * 3 + 0], qx);
        float dy = __fsub_rn(xb[j * 3 + 1], qy);
        float dz = __fsub_rn(xb[j * 3 + 2], qz);
        float d2 = __fadd_rn(__fadd_rn(__fmul_rn(dx, dx), __fmul_rn(dy, dy)), __fmul_rn(dz, dz));
        bool in = d2 < r2;
        unsigned long long m = __ballot(in);
        if (count == 0 && m) first = base + __ffsll((long long)m) - 1;
        if (in) {
            int pos = count + __popcll(m & ((1ull << lane) - 1ull));
            if (pos < K) out[pos] = j;
        }
        count += __popcll(m);
    }
    if (count < K) {
        int fillv = (count > 0) ? first : 0;  // count==0 => all idx were N => first -> 0
        for (int p = count + lane; p < K; p += 64) out[p] = fillv;
    }
}

// ---------------- fused GEMM (+gather / +affine-relu input, +stats, +maxmin output) ----------------
// X logical layout: [Cin][NCOL], col = b*S*K + s*K + k. Wt: [Cin][M] (transposed weights).
// Each block: 64 output channels (m0..m0+63) x 256 columns; acc in VGPRs; W reads are
// wave-uniform -> expect s_load scalarization.
// IN_MODE 0: gather on the fly (rel xyz + features via idx). IN_MODE 1: bf16 X + per-channel
// affine (scale,shift) + relu (i.e., previous layer's BN+ReLU applied lazily).
// OUT_MODE 0: store raw bf16 Y. OUT_MODE 1: max/min over K-groups (KG lanes) -> MX/MN.
// Always: per-channel sum/sumsq partials via shuffle-reduce + spread atomics.
template <int IN_MODE, int OUT_MODE, int KG>
__global__ __launch_bounds__(256) void gemm_kernel(
    const float* __restrict__ Wt, const __hip_bfloat16* __restrict__ Xin,
    const float* __restrict__ aff, const int* __restrict__ idx,
    const float* __restrict__ xyz, const float* __restrict__ newxyz,
    const float* __restrict__ feat, __hip_bfloat16* __restrict__ Yout,
    float* __restrict__ MX, float* __restrict__ MN,
    float* __restrict__ statS, float* __restrict__ statQ,
    int Cin, int M, long NCOL, int kshift) {
    const int m0 = blockIdx.x * 64;
    const long col = (long)blockIdx.y * 256 + threadIdx.x;
    const int lane = threadIdx.x & 63;
    const int wv = threadIdx.x >> 6;
    float acc[64];
#pragma unroll
    for (int m = 0; m < 64; ++m) acc[m] = 0.f;

    if (IN_MODE == 0) {
        long sk = col >> kshift;         // b*1024 + s
        int b = (int)(sk >> 10);
        int j = idx[col];
        const float* g = xyz + ((long)b * 8192 + j) * 3;
        const float* q = newxyz + sk * 3;
        float r0 = g[0] - q[0], r1 = g[1] - q[1], r2 = g[2] - q[2];
        const float* w0 = Wt + m0;
        const float* w1 = Wt + M + m0;
        const float* w2 = Wt + 2 * M + m0;
#pragma unroll
        for (int m = 0; m < 64; ++m) acc[m] = fmaf(w0[m], r0, acc[m]);
#pragma unroll
        for (int m = 0; m < 64; ++m) acc[m] = fmaf(w1[m], r1, acc[m]);
#pragma unroll
        for (int m = 0; m < 64; ++m) acc[m] = fmaf(w2[m], r2, acc[m]);
        const float* fb = feat + (long)b * 64 * 8192 + j;
        for (int c = 0; c < 64; ++c) {
            float xv = fb[(long)c * 8192];
            const float* wr = Wt + (long)(3 + c) * M + m0;
#pragma unroll
            for (int m = 0; m < 64; ++m) acc[m] = fmaf(wr[m], xv, acc[m]);
        }
    } else {
        const __hip_bfloat16* xc = Xin + col;
        for (int i = 0; i < Cin; ++i) {
            float xv = __bfloat162float(xc[(long)i * NCOL]);
            xv = fmaxf(fmaf(xv, aff[i], aff[Cin + i]), 0.f);  // BN affine + relu of prev layer
            const float* wr = Wt + (long)i * M + m0;
#pragma unroll
            for (int m = 0; m < 64; ++m) acc[m] = fmaf(wr[m], xv, acc[m]);
        }
    }

    // per-channel sum / sumsq (stats over raw pre-norm y, matching the reference)
    __shared__ float ldsS[4][64];
    __shared__ float ldsQ[4][64];
#pragma unroll
    for (int m = 0; m < 64; ++m) {
        float s = acc[m];
        float q = s * s;
#pragma unroll
        for (int off = 32; off; off >>= 1) {
            s += __shfl_xor(s, off, 64);
            q += __shfl_xor(q, off, 64);
        }
        if (lane == 0) { ldsS[wv][m] = s; ldsQ[wv][m] = q; }
    }
    __syncthreads();
    if (threadIdx.x < 64) {
        int m = threadIdx.x;
        float s = ldsS[0][m] + ldsS[1][m] + ldsS[2][m] + ldsS[3][m];
        float q = ldsQ[0][m] + ldsQ[1][m] + ldsQ[2][m] + ldsQ[3][m];
        int slot = (int)(blockIdx.y & 127);
        atomicAdd(statS + (size_t)(m0 + m) * 128 + slot, s);
        atomicAdd(statQ + (size_t)(m0 + m) * 128 + slot, q);
    }

    if (OUT_MODE == 0) {
#pragma unroll
        for (int m = 0; m < 64; ++m)
            Yout[(long)(m0 + m) * NCOL + col] = __float2bfloat16(acc[m]);
    } else {
        // group max/min over the K samples of one (b,s); KG lanes per group, groups aligned
#pragma unroll
        for (int m = 0; m < 64; ++m) {
            float mx = acc[m], mn = acc[m];
#pragma unroll
            for (int off = KG >> 1; off; off >>= 1) {
                mx = fmaxf(mx, __shfl_xor(mx, off, 64));
                mn = fminf(mn, __shfl_xor(mn, off, 64));
            }
            if ((lane & (KG - 1)) == 0) {
                long g = col >> kshift;  // b*1024+s
                MX[(long)(m0 + m) * 8192 + g] = mx;
                MN[(long)(m0 + m) * 8192 + g] = mn;
            }
        }
    }
}

// ---------------- finalize BN constants: scale = g/sqrt(var+eps), shift = b - mean*scale ----------------
__global__ void finalize_kernel(const float* __restrict__ sS, const float* __restrict__ sQ,
                                const float* __restrict__ g, const float* __restrict__ b,
                                float* __restrict__ aff, int C, float invCount) {
    int c = threadIdx.x + blockIdx.x * blockDim.x;
    if (c >= C) return;
    float s = 0.f, q = 0.f;
    for (int k = 0; k < 128; ++k) { s += sS[c * 128 + k]; q += sQ[c * 128 + k]; }
    float mean = s * invCount;
    float var = fmaxf(q * invCount - mean * mean, 0.f);
    float sc = g[c] / sqrtf(var + 1e-5f);
    float sh = b[c] - mean * sc;
    aff[c] = sc;
    aff[C + c] = sh;
}

// ---------------- final output: relu(norm(max/min)) -> out1 ----------------
// max_k relu(a*y+b) = relu(max(a*mx+b, a*mn+b))  (monotone affine + relu)
__global__ void final_out_kernel(const float* __restrict__ MX, const float* __restrict__ MN,
                                 const float* __restrict__ aff, float* __restrict__ out1,
                                 int Cout, int cOff) {
    long i = (long)blockIdx.x * 256 + threadIdx.x;  // over Cout*8192
    int c = (int)(i >> 13);
    int gidx = (int)(i & 8191);
    int b = gidx >> 10, s = gidx & 1023;
    float sc = aff[c], sh = aff[Cout + c];
    float v = fmaxf(fmaxf(sc * MX[i] + sh, sc * MN[i] + sh), 0.f);
    out1[((long)b * 384 + cOff + c) * 1024 + s] = v;
}

// ---------------- host ----------------
extern "C" void kernel_launch(void* const* d_in, const int* in_sizes, int n_in,
                              void* d_out, int out_size, void* d_ws, size_t ws_size,
                              hipStream_t stream) {
    const float* xyz = (const float*)d_in[0];
    const float* feat = (const float*)d_in[1];
    const float *W[6], *G[6], *Bi[6];
    for (int l = 0; l < 6; ++l) {
        W[l] = (const float*)d_in[2 + l * 3];
        G[l] = (const float*)d_in[3 + l * 3];
        Bi[l] = (const float*)d_in[4 + l * 3];
    }
    char* ws = (char*)d_ws;
    float* out0 = (float*)d_out;              // new_xyz [8][1024][3]
    float* out1 = (float*)d_out + 24576;      // features [8][384][1024]

    float* wt = (float*)(ws + OFF_WT);
    float* stats = (float*)(ws + OFF_STATS);
    float* affine = (float*)(ws + OFF_AFF);
    float* pts = (float*)(ws + OFF_PTS);
    int* idx0 = (int*)(ws + OFF_IDX0);
    int* idx1 = (int*)(ws + OFF_IDX1);
    float* mx = (float*)(ws + OFF_MX);
    float* mn = (float*)(ws + OFF_MN);
    __hip_bfloat16* y0 = (__hip_bfloat16*)(ws + OFF_Y0);
    __hip_bfloat16* y1 = (__hip_bfloat16*)(ws + OFF_Y1);

    hipMemsetAsync(stats, 0, STATS_BYTES, stream);
    prep_weights<<<242, 256, 0, stream>>>(W[0], W[1], W[2], W[3], W[4], W[5], wt);
    fps_kernel<<<8, 1024, 0, stream>>>(xyz, out0, pts);

    const int wtOff[6] = {0, 4288, 8384, 16576, 20864, 29056};
    int stOff[6], afOff[6];
    {
        const int Cs[6] = {64, 64, 128, 64, 128, 256};
        int so = 0, ao = 0;
        for (int l = 0; l < 6; ++l) {
            stOff[l] = so; so += Cs[l] * 256;
            afOff[l] = ao; ao += Cs[l] * 2;
        }
    }

    for (int br = 0; br < 2; ++br) {
        const int K = br ? 64 : 32;
        const int kshift = br ? 6 : 5;
        const float radius = br ? 0.8f : 0.4f;
        const long NCOL = 8L * 1024 * K;
        int* idx = br ? idx1 : idx0;
        const int l0 = br * 3, l1 = br * 3 + 1, l2 = br * 3 + 2;
        const int M1 = br ? 128 : 64;   // layer1 out channels (= layer2 Cin)
        const int M2 = br ? 256 : 128;  // layer2 out channels
        const float invCount = 1.f / (float)NCOL;
        const int ntiles = (int)(NCOL / 256);

        ball_query_kernel<<<2048, 256, 0, stream>>>(xyz, out0, idx, radius * radius, K);

        // L0: gathered input -> y0 (raw), stats
        gemm_kernel<0, 0, 1><<<dim3(1, ntiles), 256, 0, stream>>>(
            wt + wtOff[l0], nullptr, nullptr, idx, xyz, out0, feat, y0, nullptr, nullptr,
            stats + stOff[l0], stats + stOff[l0] + 64 * 128, 67, 64, NCOL, kshift);
        finalize_kernel<<<1, 256, 0, stream>>>(stats + stOff[l0], stats + stOff[l0] + 64 * 128,
                                               G[l0], Bi[l0], affine + afOff[l0], 64, invCount);

        // L1: affine(relu(y0)) -> y1 (raw), stats
        gemm_kernel<1, 0, 1><<<dim3(M1 / 64, ntiles), 256, 0, stream>>>(
            wt + wtOff[l1], y0, affine + afOff[l0], nullptr, nullptr, nullptr, nullptr, y1,
            nullptr, nullptr, stats + stOff[l1], stats + stOff[l1] + M1 * 128, 64, M1, NCOL, kshift);
        finalize_kernel<<<1, 256, 0, stream>>>(stats + stOff[l1], stats + stOff[l1] + M1 * 128,
                                               G[l1], Bi[l1], affine + afOff[l1], M1, invCount);

        // L2: affine(relu(y1)) -> max/min over K (y2 never materialized), stats
        if (br == 0)
            gemm_kernel<1, 1, 32><<<dim3(M2 / 64, ntiles), 256, 0, stream>>>(
                wt + wtOff[l2], y1, affine + afOff[l1], nullptr, nullptr, nullptr, nullptr,
                nullptr, mx, mn, stats + stOff[l2], stats + stOff[l2] + M2 * 128, M1, M2, NCOL,
                kshift);
        else
            gemm_kernel<1, 1, 64><<<dim3(M2 / 64, ntiles), 256, 0, stream>>>(
                wt + wtOff[l2], y1, affine + afOff[l1], nullptr, nullptr, nullptr, nullptr,
                nullptr, mx, mn, stats + stOff[l2], stats + stOff[l2] + M2 * 128, M1, M2, NCOL,
                kshift);
        finalize_kernel<<<1, 256, 0, stream>>>(stats + stOff[l2], stats + stOff[l2] + M2 * 128,
                                               G[l2], Bi[l2], affine + afOff[l2], M2, invCount);

        final_out_kernel<<<(M2 * 8192) / 256, 256, 0, stream>>>(mx, mn, affine + afOff[l2], out1,
                                                                M2, br ? 128 : 0);
    }
}

// Round 2
// 2606.067 us; speedup vs baseline: 1.1498x; 1.1498x over previous
//
#include <hip/hip_runtime.h>
#include <hip/hip_bf16.h>
#include <cstdint>

// Problem constants
// B=8, N=8192, S=1024 (npoint), C=64 features
// branch0: radius 0.4, K=32, layers 64x67, 64x64, 128x64
// branch1: radius 0.8, K=64, layers 64x67, 128x64, 256x128

// ---------------- workspace layout (bytes) ----------------
static const size_t OFF_WT    = 0;          // transposed weights: 61824 floats (247 KB)
static const size_t OFF_STATS = 262144;     // 704 ch * 128 slots * 2 * 4B
static const size_t STATS_BYTES = 720896;
static const size_t OFF_AFF   = 1048576;    // per-layer scale/shift: 1408 floats
static const size_t OFF_IDX0  = 2097152;    // 8*1024*32 ints (1 MB)
static const size_t OFF_IDX1  = 3145728;    // 8*1024*64 ints (2 MB)
static const size_t OFF_MX    = 5242880;    // 256*8192 fp32 (8 MB)
static const size_t OFF_MN    = 13631488;   // 8 MB
static const size_t OFF_Y0    = 22020096;   // bf16, 64ch * 524288 (64 MB)
static const size_t OFF_Y1    = 90177536;   // bf16, 128ch * 524288 (128 MB); end ~224.4 MB

// ---------------- weight transpose: w[M][K] -> wt[K][M] ----------------
__global__ void prep_weights(const float* __restrict__ w0, const float* __restrict__ w1,
                             const float* __restrict__ w2, const float* __restrict__ w3,
                             const float* __restrict__ w4, const float* __restrict__ w5,
                             float* __restrict__ wt) {
    int id = blockIdx.x * 256 + threadIdx.x;
    const int sz[6] = {4288, 4096, 8192, 4288, 8192, 32768};
    const int Ms[6] = {64, 64, 128, 64, 128, 256};
    const int Ks[6] = {67, 64, 64, 67, 64, 128};
    const float* wp[6] = {w0, w1, w2, w3, w4, w5};
    int off = 0;
    for (int l = 0; l < 6; ++l) {
        if (id < off + sz[l]) {
            int e = id - off;
            int K = Ks[l], M = Ms[l];
            int m = e / K, i = e - m * K;
            wt[off + i * M + m] = wp[l][e];
            return;
        }
        off += sz[l];
    }
}

// ---------------- FPS: one block (512 threads, 8 waves) per batch ----------------
// All 8193 pts staged in LDS (98 KB). Thread t owns 16 pts (strided); t0 additionally
// owns the mean point (pts idx 0, checked FIRST for first-occurrence tie-break).
// Per iteration: dist update + packed-u64 wave argmax -> per-wave slot in
// parity-double-buffered LDS -> ONE barrier -> every lane redundantly reduces the 8
// slots via width-8 xor shuffles -> centroid broadcast-read from LDS.
// Mean is computed by bit-exact replication of the v1 (1024-thread) reduction tree,
// so the FPS trajectory is bit-identical to the known-passing v1 kernel.
__global__ __launch_bounds__(512) void fps_kernel(const float* __restrict__ xyz,
                                                  float* __restrict__ newxyz) {
    const int b = blockIdx.x;
    const int t = threadIdx.x;
    const int lane = t & 63, wv = t >> 6;  // wv 0..7
    const float* xb = xyz + (size_t)b * 8192 * 3;

    __shared__ float ptsx[8200];
    __shared__ float ptsy[8200];
    __shared__ float ptsz[8200];
    __shared__ float ldsM[16][3];
    __shared__ float meanv[3];
    __shared__ unsigned long long sKey[2][8];

    // ---- load own 16 points, stage all points to LDS ----
    float px[16], py[16], pz[16], d[16];
#pragma unroll
    for (int j = 0; j < 16; ++j) {
        int q = t + 512 * j;  // xyz index; pts index = q+1
        px[j] = xb[q * 3 + 0];
        py[j] = xb[q * 3 + 1];
        pz[j] = xb[q * 3 + 2];
        d[j] = 1e10f;
        ptsx[q + 1] = px[j];
        ptsy[q + 1] = py[j];
        ptsz[q + 1] = pz[j];
    }

    // ---- mean: bit-identical replication of v1's 1024-partial tree ----
    // v1 partial[t_old] = sum_j xyz[((t_old+1023)&1023) + 1024j], j ascending.
    // Thread t plays roles t_old = t (A, old wave wv) and t_old = t+512 (B, old wave wv+8).
    float sxA = 0.f, syA = 0.f, szA = 0.f;
    float sxB = 0.f, syB = 0.f, szB = 0.f;
    int uA = (t + 1023) & 1023;
    int uB = (t + 511) & 1023;
#pragma unroll
    for (int j = 0; j < 8; ++j) {
        int ia = uA + 1024 * j;
        int ib = uB + 1024 * j;
        sxA += xb[ia * 3 + 0]; syA += xb[ia * 3 + 1]; szA += xb[ia * 3 + 2];
        sxB += xb[ib * 3 + 0]; syB += xb[ib * 3 + 1]; szB += xb[ib * 3 + 2];
    }
#pragma unroll
    for (int off = 32; off; off >>= 1) {
        sxA += __shfl_xor(sxA, off, 64);
        syA += __shfl_xor(syA, off, 64);
        szA += __shfl_xor(szA, off, 64);
        sxB += __shfl_xor(sxB, off, 64);
        syB += __shfl_xor(syB, off, 64);
        szB += __shfl_xor(szB, off, 64);
    }
    if (lane == 0) {
        ldsM[wv][0] = sxA; ldsM[wv][1] = syA; ldsM[wv][2] = szA;
        ldsM[wv + 8][0] = sxB; ldsM[wv + 8][1] = syB; ldsM[wv + 8][2] = szB;
    }
    __syncthreads();
    if (t < 3) {
        float s = 0.f;
        for (int w = 0; w < 16; ++w) s += ldsM[w][t];
        meanv[t] = s * (1.f / 8192.f);
    }
    __syncthreads();
    float cx = meanv[0], cy = meanv[1], cz = meanv[2];
    const float mmx = cx, mmy = cy, mmz = cz;  // the mean point (pts idx 0), owned by t0
    float dm = 1e10f;
    if (t == 0) { ptsx[0] = cx; ptsy[0] = cy; ptsz[0] = cz; }
    __syncthreads();

    for (int it = 0; it < 1024; ++it) {
        if (t == 0) {
            float* o = newxyz + ((size_t)b * 1024 + it) * 3;
            o[0] = cx; o[1] = cy; o[2] = cz;
        }
        float bv = -1e30f;
        int bi = 0;
        if (t == 0) {
            // mean point is pts idx 0 -> must be considered FIRST (smallest index)
            float dx = __fsub_rn(mmx, cx);
            float dy = __fsub_rn(mmy, cy);
            float dz = __fsub_rn(mmz, cz);
            float dd = __fadd_rn(__fadd_rn(__fmul_rn(dx, dx), __fmul_rn(dy, dy)), __fmul_rn(dz, dz));
            dm = fminf(dm, dd);
            bv = dm; bi = 0;
        }
#pragma unroll
        for (int j = 0; j < 16; ++j) {
            // no-fma ordering, identical to v1 (tracks the XLA reference)
            float dx = __fsub_rn(px[j], cx);
            float dy = __fsub_rn(py[j], cy);
            float dz = __fsub_rn(pz[j], cz);
            float dd = __fadd_rn(__fadd_rn(__fmul_rn(dx, dx), __fmul_rn(dy, dy)), __fmul_rn(dz, dz));
            float nd = fminf(d[j], dd);
            d[j] = nd;
            if (nd > bv) { bv = nd; bi = t + 512 * j + 1; }  // ascending idx + strict > = first occurrence
        }
        unsigned long long key =
            ((unsigned long long)__float_as_uint(bv) << 32) | (unsigned)(8192 - bi);
#pragma unroll
        for (int off = 32; off; off >>= 1) {
            unsigned long long o = __shfl_xor(key, off, 64);
            if (o > key) key = o;
        }
        int par = it & 1;
        if (lane == 0) sKey[par][wv] = key;
        __syncthreads();  // the ONLY barrier per iteration (slots parity-double-buffered)
        unsigned long long k2 = sKey[par][lane & 7];
#pragma unroll
        for (int off = 1; off < 8; off <<= 1) {
            unsigned long long o = __shfl_xor(k2, off, 8);
            if (o > k2) k2 = o;
        }
        int far = 8192 - (int)(unsigned)(k2 & 0xffffffffull);
        cx = ptsx[far];  // uniform LDS broadcast
        cy = ptsy[far];
        cz = ptsz[far];
    }
}

// ---------------- ball query: one wave per query ----------------
__global__ void ball_query_kernel(const float* __restrict__ xyz, const float* __restrict__ newxyz,
                                  int* __restrict__ idxout, float r2, int K) {
    int wid = (blockIdx.x * blockDim.x + threadIdx.x) >> 6;  // query id, 0..8191
    int lane = threadIdx.x & 63;
    int b = wid >> 10;
    const float* q = newxyz + (size_t)wid * 3;
    float qx = q[0], qy = q[1], qz = q[2];
    const float* xb = xyz + (size_t)b * 8192 * 3;
    int* out = idxout + (size_t)wid * K;
    int count = 0;
    int first = 0;
    for (int base = 0; base < 8192 && count < K; base += 64) {
        int j = base + lane;
        float dx = __fsub_rn(xb[j * 3 + 0], qx);
        float dy = __fsub_rn(xb[j * 3 + 1], qy);
        float dz = __fsub_rn(xb[j * 3 + 2], qz);
        float d2 = __fadd_rn(__fadd_rn(__fmul_rn(dx, dx), __fmul_rn(dy, dy)), __fmul_rn(dz, dz));
        bool in = d2 < r2;
        unsigned long long m = __ballot(in);
        if (count == 0 && m) first = base + __ffsll((long long)m) - 1;
        if (in) {
            int pos = count + __popcll(m & ((1ull << lane) - 1ull));
            if (pos < K) out[pos] = j;
        }
        count += __popcll(m);
    }
    if (count < K) {
        int fillv = (count > 0) ? first : 0;  // count==0 => all idx were N => first -> 0
        for (int p = count + lane; p < K; p += 64) out[p] = fillv;
    }
}

// ---------------- fused GEMM (+gather / +affine-relu input, +stats, +maxmin output) ----------------
// X logical layout: [Cin][NCOL], col = b*S*K + s*K + k. Wt: [Cin][M] (transposed weights).
// Each block: 64 output channels (m0..m0+63) x 256 columns; acc in VGPRs; W reads are
// wave-uniform -> expect s_load scalarization.
// IN_MODE 0: gather on the fly (rel xyz + features via idx). IN_MODE 1: bf16 X + per-channel
// affine (scale,shift) + relu (i.e., previous layer's BN+ReLU applied lazily).
// OUT_MODE 0: store raw bf16 Y. OUT_MODE 1: max/min over K-groups (KG lanes) -> MX/MN.
// Always: per-channel sum/sumsq partials via shuffle-reduce + spread atomics.
template <int IN_MODE, int OUT_MODE, int KG>
__global__ __launch_bounds__(256) void gemm_kernel(
    const float* __restrict__ Wt, const __hip_bfloat16* __restrict__ Xin,
    const float* __restrict__ aff, const int* __restrict__ idx,
    const float* __restrict__ xyz, const float* __restrict__ newxyz,
    const float* __restrict__ feat, __hip_bfloat16* __restrict__ Yout,
    float* __restrict__ MX, float* __restrict__ MN,
    float* __restrict__ statS, float* __restrict__ statQ,
    int Cin, int M, long NCOL, int kshift) {
    const int m0 = blockIdx.x * 64;
    const long col = (long)blockIdx.y * 256 + threadIdx.x;
    const int lane = threadIdx.x & 63;
    const int wv = threadIdx.x >> 6;
    float acc[64];
#pragma unroll
    for (int m = 0; m < 64; ++m) acc[m] = 0.f;

    if (IN_MODE == 0) {
        long sk = col >> kshift;         // b*1024 + s
        int b = (int)(sk >> 10);
        int j = idx[col];
        const float* g = xyz + ((long)b * 8192 + j) * 3;
        const float* q = newxyz + sk * 3;
        float r0 = g[0] - q[0], r1 = g[1] - q[1], r2 = g[2] - q[2];
        const float* w0 = Wt + m0;
        const float* w1 = Wt + M + m0;
        const float* w2 = Wt + 2 * M + m0;
#pragma unroll
        for (int m = 0; m < 64; ++m) acc[m] = fmaf(w0[m], r0, acc[m]);
#pragma unroll
        for (int m = 0; m < 64; ++m) acc[m] = fmaf(w1[m], r1, acc[m]);
#pragma unroll
        for (int m = 0; m < 64; ++m) acc[m] = fmaf(w2[m], r2, acc[m]);
        const float* fb = feat + (long)b * 64 * 8192 + j;
        for (int c = 0; c < 64; ++c) {
            float xv = fb[(long)c * 8192];
            const float* wr = Wt + (long)(3 + c) * M + m0;
#pragma unroll
            for (int m = 0; m < 64; ++m) acc[m] = fmaf(wr[m], xv, acc[m]);
        }
    } else {
        const __hip_bfloat16* xc = Xin + col;
        for (int i = 0; i < Cin; ++i) {
            float xv = __bfloat162float(xc[(long)i * NCOL]);
            xv = fmaxf(fmaf(xv, aff[i], aff[Cin + i]), 0.f);  // BN affine + relu of prev layer
            const float* wr = Wt + (long)i * M + m0;
#pragma unroll
            for (int m = 0; m < 64; ++m) acc[m] = fmaf(wr[m], xv, acc[m]);
        }
    }

    // per-channel sum / sumsq (stats over raw pre-norm y, matching the reference)
    __shared__ float ldsS[4][64];
    __shared__ float ldsQ[4][64];
#pragma unroll
    for (int m = 0; m < 64; ++m) {
        float s = acc[m];
        float q = s * s;
#pragma unroll
        for (int off = 32; off; off >>= 1) {
            s += __shfl_xor(s, off, 64);
            q += __shfl_xor(q, off, 64);
        }
        if (lane == 0) { ldsS[wv][m] = s; ldsQ[wv][m] = q; }
    }
    __syncthreads();
    if (threadIdx.x < 64) {
        int m = threadIdx.x;
        float s = ldsS[0][m] + ldsS[1][m] + ldsS[2][m] + ldsS[3][m];
        float q = ldsQ[0][m] + ldsQ[1][m] + ldsQ[2][m] + ldsQ[3][m];
        int slot = (int)(blockIdx.y & 127);
        atomicAdd(statS + (size_t)(m0 + m) * 128 + slot, s);
        atomicAdd(statQ + (size_t)(m0 + m) * 128 + slot, q);
    }

    if (OUT_MODE == 0) {
#pragma unroll
        for (int m = 0; m < 64; ++m)
            Yout[(long)(m0 + m) * NCOL + col] = __float2bfloat16(acc[m]);
    } else {
        // group max/min over the K samples of one (b,s); KG lanes per group, groups aligned
#pragma unroll
        for (int m = 0; m < 64; ++m) {
            float mx = acc[m], mn = acc[m];
#pragma unroll
            for (int off = KG >> 1; off; off >>= 1) {
                mx = fmaxf(mx, __shfl_xor(mx, off, 64));
                mn = fminf(mn, __shfl_xor(mn, off, 64));
            }
            if ((lane & (KG - 1)) == 0) {
                long g = col >> kshift;  // b*1024+s
                MX[(long)(m0 + m) * 8192 + g] = mx;
                MN[(long)(m0 + m) * 8192 + g] = mn;
            }
        }
    }
}

// ---------------- finalize BN constants: scale = g/sqrt(var+eps), shift = b - mean*scale ----------------
__global__ void finalize_kernel(const float* __restrict__ sS, const float* __restrict__ sQ,
                                const float* __restrict__ g, const float* __restrict__ b,
                                float* __restrict__ aff, int C, float invCount) {
    int c = threadIdx.x + blockIdx.x * blockDim.x;
    if (c >= C) return;
    float s = 0.f, q = 0.f;
    for (int k = 0; k < 128; ++k) { s += sS[c * 128 + k]; q += sQ[c * 128 + k]; }
    float mean = s * invCount;
    float var = fmaxf(q * invCount - mean * mean, 0.f);
    float sc = g[c] / sqrtf(var + 1e-5f);
    float sh = b[c] - mean * sc;
    aff[c] = sc;
    aff[C + c] = sh;
}

// ---------------- final output: relu(norm(max/min)) -> out1 ----------------
// max_k relu(a*y+b) = relu(max(a*mx+b, a*mn+b))  (monotone affine + relu)
__global__ void final_out_kernel(const float* __restrict__ MX, const float* __restrict__ MN,
                                 const float* __restrict__ aff, float* __restrict__ out1,
                                 int Cout, int cOff) {
    long i = (long)blockIdx.x * 256 + threadIdx.x;  // over Cout*8192
    int c = (int)(i >> 13);
    int gidx = (int)(i & 8191);
    int b = gidx >> 10, s = gidx & 1023;
    float sc = aff[c], sh = aff[Cout + c];
    float v = fmaxf(fmaxf(sc * MX[i] + sh, sc * MN[i] + sh), 0.f);
    out1[((long)b * 384 + cOff + c) * 1024 + s] = v;
}

// ---------------- host ----------------
extern "C" void kernel_launch(void* const* d_in, const int* in_sizes, int n_in,
                              void* d_out, int out_size, void* d_ws, size_t ws_size,
                              hipStream_t stream) {
    const float* xyz = (const float*)d_in[0];
    const float* feat = (const float*)d_in[1];
    const float *W[6], *G[6], *Bi[6];
    for (int l = 0; l < 6; ++l) {
        W[l] = (const float*)d_in[2 + l * 3];
        G[l] = (const float*)d_in[3 + l * 3];
        Bi[l] = (const float*)d_in[4 + l * 3];
    }
    char* ws = (char*)d_ws;
    float* out0 = (float*)d_out;              // new_xyz [8][1024][3]
    float* out1 = (float*)d_out + 24576;      // features [8][384][1024]

    float* wt = (float*)(ws + OFF_WT);
    float* stats = (float*)(ws + OFF_STATS);
    float* affine = (float*)(ws + OFF_AFF);
    int* idx0 = (int*)(ws + OFF_IDX0);
    int* idx1 = (int*)(ws + OFF_IDX1);
    float* mx = (float*)(ws + OFF_MX);
    float* mn = (float*)(ws + OFF_MN);
    __hip_bfloat16* y0 = (__hip_bfloat16*)(ws + OFF_Y0);
    __hip_bfloat16* y1 = (__hip_bfloat16*)(ws + OFF_Y1);

    hipMemsetAsync(stats, 0, STATS_BYTES, stream);
    prep_weights<<<242, 256, 0, stream>>>(W[0], W[1], W[2], W[3], W[4], W[5], wt);
    fps_kernel<<<8, 512, 0, stream>>>(xyz, out0);

    const int wtOff[6] = {0, 4288, 8384, 16576, 20864, 29056};
    int stOff[6], afOff[6];
    {
        const int Cs[6] = {64, 64, 128, 64, 128, 256};
        int so = 0, ao = 0;
        for (int l = 0; l < 6; ++l) {
            stOff[l] = so; so += Cs[l] * 256;
            afOff[l] = ao; ao += Cs[l] * 2;
        }
    }

    for (int br = 0; br < 2; ++br) {
        const int K = br ? 64 : 32;
        const int kshift = br ? 6 : 5;
        const float radius = br ? 0.8f : 0.4f;
        const long NCOL = 8L * 1024 * K;
        int* idx = br ? idx1 : idx0;
        const int l0 = br * 3, l1 = br * 3 + 1, l2 = br * 3 + 2;
        const int M1 = br ? 128 : 64;   // layer1 out channels (= layer2 Cin)
        const int M2 = br ? 256 : 128;  // layer2 out channels
        const float invCount = 1.f / (float)NCOL;
        const int ntiles = (int)(NCOL / 256);

        ball_query_kernel<<<2048, 256, 0, stream>>>(xyz, out0, idx, radius * radius, K);

        // L0: gathered input -> y0 (raw), stats
        gemm_kernel<0, 0, 1><<<dim3(1, ntiles), 256, 0, stream>>>(
            wt + wtOff[l0], nullptr, nullptr, idx, xyz, out0, feat, y0, nullptr, nullptr,
            stats + stOff[l0], stats + stOff[l0] + 64 * 128, 67, 64, NCOL, kshift);
        finalize_kernel<<<1, 256, 0, stream>>>(stats + stOff[l0], stats + stOff[l0] + 64 * 128,
                                               G[l0], Bi[l0], affine + afOff[l0], 64, invCount);

        // L1: affine(relu(y0)) -> y1 (raw), stats
        gemm_kernel<1, 0, 1><<<dim3(M1 / 64, ntiles), 256, 0, stream>>>(
            wt + wtOff[l1], y0, affine + afOff[l0], nullptr, nullptr, nullptr, nullptr, y1,
            nullptr, nullptr, stats + stOff[l1], stats + stOff[l1] + M1 * 128, 64, M1, NCOL, kshift);
        finalize_kernel<<<1, 256, 0, stream>>>(stats + stOff[l1], stats + stOff[l1] + M1 * 128,
                                               G[l1], Bi[l1], affine + afOff[l1], M1, invCount);

        // L2: affine(relu(y1)) -> max/min over K (y2 never materialized), stats
        if (br == 0)
            gemm_kernel<1, 1, 32><<<dim3(M2 / 64, ntiles), 256, 0, stream>>>(
                wt + wtOff[l2], y1, affine + afOff[l1], nullptr, nullptr, nullptr, nullptr,
                nullptr, mx, mn, stats + stOff[l2], stats + stOff[l2] + M2 * 128, M1, M2, NCOL,
                kshift);
        else
            gemm_kernel<1, 1, 64><<<dim3(M2 / 64, ntiles), 256, 0, stream>>>(
                wt + wtOff[l2], y1, affine + afOff[l1], nullptr, nullptr, nullptr, nullptr,
                nullptr, mx, mn, stats + stOff[l2], stats + stOff[l2] + M2 * 128, M1, M2, NCOL,
                kshift);
        finalize_kernel<<<1, 256, 0, stream>>>(stats + stOff[l2], stats + stOff[l2] + M2 * 128,
                                               G[l2], Bi[l2], affine + afOff[l2], M2, invCount);

        final_out_kernel<<<(M2 * 8192) / 256, 256, 0, stream>>>(mx, mn, affine + afOff[l2], out1,
                                                                M2, br ? 128 : 0);
    }
}

// Round 3
// 1905.278 us; speedup vs baseline: 1.5727x; 1.3678x over previous
//
#include <hip/hip_runtime.h>
#include <hip/hip_bf16.h>
#include <cstdint>

// B=8, N=8192, S=1024, C=64
// branch0: r=0.4, K=32, layers 64x67, 64x64, 128x64
// branch1: r=0.8, K=64, layers 64x67, 128x64, 256x128

typedef __attribute__((ext_vector_type(8))) short short8;
typedef __attribute__((ext_vector_type(4))) float f32x4;

__device__ __forceinline__ float bf2f(unsigned short u) {
    return __uint_as_float(((unsigned)u) << 16);
}
__device__ __forceinline__ unsigned short f2bf(float f) {
    unsigned u = __float_as_uint(f);
    return (unsigned short)((u + 0x7fffu + ((u >> 16) & 1u)) >> 16);  // RNE
}

// ---------------- workspace layout (bytes); peak = 224,395,264 (same as v2) ----
static const size_t OFF_WBF   = 0;          // packed bf16 weights, 65536 elems (128 KB)
static const size_t OFF_STATS = 262144;     // 704 ch * 128 slots * 2 * 4B
static const size_t STATS_BYTES = 720896;
static const size_t OFF_AFF   = 1048576;    // per-layer scale/shift
static const size_t OFF_IDX0  = 2097152;    // 8*1024*32 ints
static const size_t OFF_IDX1  = 3145728;    // 8*1024*64 ints
static const size_t OFF_MX    = 5242880;    // 256*8192 fp32
static const size_t OFF_MN    = 13631488;
static const size_t OFF_Y0    = 22020096;   // bf16 X^T [NCOL][64]  (max 67 MB)
static const size_t OFF_Y1    = 90177536;   // bf16 X^T [NCOL][128] (max 134 MB)
static const size_t OFF_FEATT = 211812352;  // bf16 [8*8192][96] = 12.58 MB, overlaps Y1 tail:
// featTp written before branches, last read in br1-L0; Y1 bytes beyond 121.6 MB are only
// written by br1-L1 which runs after br1-L0. br0 uses only the first 33.5 MB of Y1.

// ---------------- weight pack: w[M][K] f32 -> wb[Mp][Kp] bf16 (zero pad) --------
__global__ void prep_wbf(const float* __restrict__ w0, const float* __restrict__ w1,
                         const float* __restrict__ w2, const float* __restrict__ w3,
                         const float* __restrict__ w4, const float* __restrict__ w5,
                         unsigned short* __restrict__ wb) {
    int id = blockIdx.x * 256 + threadIdx.x;  // 0..65535
    const int psz[6] = {6144, 4096, 8192, 6144, 8192, 32768};
    const int Kp[6] = {96, 64, 64, 96, 64, 128};
    const int Ks[6] = {67, 64, 64, 67, 64, 128};
    const float* wp[6] = {w0, w1, w2, w3, w4, w5};
    int off = 0;
    for (int l = 0; l < 6; ++l) {
        if (id < off + psz[l]) {
            int e = id - off;
            int m = e / Kp[l], k = e - m * Kp[l];
            float v = (k < Ks[l]) ? wp[l][m * Ks[l] + k] : 0.f;
            wb[id] = f2bf(v);
            return;
        }
        off += psz[l];
    }
}

// ---------------- featTp: [8][8192][96] bf16; c0..2 = xyz, c3..66 = feat, rest 0 --
__global__ __launch_bounds__(256) void feat_transpose(const float* __restrict__ xyz,
                                                      const float* __restrict__ feat,
                                                      unsigned short* __restrict__ ft) {
    __shared__ float tile[64][65];
    const int b = blockIdx.y;
    const int j0 = blockIdx.x * 64;
    const int tid = threadIdx.x;
#pragma unroll
    for (int i = 0; i < 16; ++i) {
        int e = i * 256 + tid;
        int c = e >> 6, j = e & 63;
        tile[j][c] = feat[((size_t)b * 64 + c) * 8192 + j0 + j];
    }
    __syncthreads();
#pragma unroll
    for (int i = 0; i < 16; ++i) {
        int e = i * 256 + tid;
        int j = e >> 6, c = e & 63;
        ft[((size_t)(b * 8192 + j0 + j)) * 96 + 3 + c] = f2bf(tile[j][c]);
    }
    // xyz channels + zero pad
    if (tid < 64) {
        int j = tid;
        size_t base = ((size_t)(b * 8192 + j0 + j)) * 96;
        const float* xp = xyz + ((size_t)b * 8192 + j0 + j) * 3;
        ft[base + 0] = f2bf(xp[0]);
        ft[base + 1] = f2bf(xp[1]);
        ft[base + 2] = f2bf(xp[2]);
    } else if (tid < 128) {
        int j = tid - 64;
        size_t base = ((size_t)(b * 8192 + j0 + j)) * 96;
        for (int c = 67; c < 96; ++c) ft[base + c] = 0;
    } else if (tid < 192) {
        int j = tid - 64;  // j 64..127? no: second half of pad rows
    }
    // pad rows 0..63 done above for tid 64..127; do remaining pad rows 32..63? (none: j covers 0..63)
}

// ---------------- FPS (unchanged from v2, known-good) --------------------------
__global__ __launch_bounds__(512) void fps_kernel(const float* __restrict__ xyz,
                                                  float* __restrict__ newxyz) {
    const int b = blockIdx.x;
    const int t = threadIdx.x;
    const int lane = t & 63, wv = t >> 6;
    const float* xb = xyz + (size_t)b * 8192 * 3;

    __shared__ float ptsx[8200];
    __shared__ float ptsy[8200];
    __shared__ float ptsz[8200];
    __shared__ float ldsM[16][3];
    __shared__ float meanv[3];
    __shared__ unsigned long long sKey[2][8];

    float px[16], py[16], pz[16], d[16];
#pragma unroll
    for (int j = 0; j < 16; ++j) {
        int q = t + 512 * j;
        px[j] = xb[q * 3 + 0];
        py[j] = xb[q * 3 + 1];
        pz[j] = xb[q * 3 + 2];
        d[j] = 1e10f;
        ptsx[q + 1] = px[j];
        ptsy[q + 1] = py[j];
        ptsz[q + 1] = pz[j];
    }
    float sxA = 0.f, syA = 0.f, szA = 0.f;
    float sxB = 0.f, syB = 0.f, szB = 0.f;
    int uA = (t + 1023) & 1023;
    int uB = (t + 511) & 1023;
#pragma unroll
    for (int j = 0; j < 8; ++j) {
        int ia = uA + 1024 * j;
        int ib = uB + 1024 * j;
        sxA += xb[ia * 3 + 0]; syA += xb[ia * 3 + 1]; szA += xb[ia * 3 + 2];
        sxB += xb[ib * 3 + 0]; syB += xb[ib * 3 + 1]; szB += xb[ib * 3 + 2];
    }
#pragma unroll
    for (int off = 32; off; off >>= 1) {
        sxA += __shfl_xor(sxA, off, 64);
        syA += __shfl_xor(syA, off, 64);
        szA += __shfl_xor(szA, off, 64);
        sxB += __shfl_xor(sxB, off, 64);
        syB += __shfl_xor(syB, off, 64);
        szB += __shfl_xor(szB, off, 64);
    }
    if (lane == 0) {
        ldsM[wv][0] = sxA; ldsM[wv][1] = syA; ldsM[wv][2] = szA;
        ldsM[wv + 8][0] = sxB; ldsM[wv + 8][1] = syB; ldsM[wv + 8][2] = szB;
    }
    __syncthreads();
    if (t < 3) {
        float s = 0.f;
        for (int w = 0; w < 16; ++w) s += ldsM[w][t];
        meanv[t] = s * (1.f / 8192.f);
    }
    __syncthreads();
    float cx = meanv[0], cy = meanv[1], cz = meanv[2];
    const float mmx = cx, mmy = cy, mmz = cz;
    float dm = 1e10f;
    if (t == 0) { ptsx[0] = cx; ptsy[0] = cy; ptsz[0] = cz; }
    __syncthreads();

    for (int it = 0; it < 1024; ++it) {
        if (t == 0) {
            float* o = newxyz + ((size_t)b * 1024 + it) * 3;
            o[0] = cx; o[1] = cy; o[2] = cz;
        }
        float bv = -1e30f;
        int bi = 0;
        if (t == 0) {
            float dx = __fsub_rn(mmx, cx);
            float dy = __fsub_rn(mmy, cy);
            float dz = __fsub_rn(mmz, cz);
            float dd = __fadd_rn(__fadd_rn(__fmul_rn(dx, dx), __fmul_rn(dy, dy)), __fmul_rn(dz, dz));
            dm = fminf(dm, dd);
            bv = dm; bi = 0;
        }
#pragma unroll
        for (int j = 0; j < 16; ++j) {
            float dx = __fsub_rn(px[j], cx);
            float dy = __fsub_rn(py[j], cy);
            float dz = __fsub_rn(pz[j], cz);
            float dd = __fadd_rn(__fadd_rn(__fmul_rn(dx, dx), __fmul_rn(dy, dy)), __fmul_rn(dz, dz));
            float nd = fminf(d[j], dd);
            d[j] = nd;
            if (nd > bv) { bv = nd; bi = t + 512 * j + 1; }
        }
        unsigned long long key =
            ((unsigned long long)__float_as_uint(bv) << 32) | (unsigned)(8192 - bi);
#pragma unroll
        for (int off = 32; off; off >>= 1) {
            unsigned long long o = __shfl_xor(key, off, 64);
            if (o > key) key = o;
        }
        int par = it & 1;
        if (lane == 0) sKey[par][wv] = key;
        __syncthreads();
        unsigned long long k2 = sKey[par][lane & 7];
#pragma unroll
        for (int off = 1; off < 8; off <<= 1) {
            unsigned long long o = __shfl_xor(k2, off, 8);
            if (o > k2) k2 = o;
        }
        int far = 8192 - (int)(unsigned)(k2 & 0xffffffffull);
        cx = ptsx[far];
        cy = ptsy[far];
        cz = ptsz[far];
    }
}

// ---------------- ball query (unchanged) ---------------------------------------
__global__ void ball_query_kernel(const float* __restrict__ xyz, const float* __restrict__ newxyz,
                                  int* __restrict__ idxout, float r2, int K) {
    int wid = (blockIdx.x * blockDim.x + threadIdx.x) >> 6;
    int lane = threadIdx.x & 63;
    int b = wid >> 10;
    const float* q = newxyz + (size_t)wid * 3;
    float qx = q[0], qy = q[1], qz = q[2];
    const float* xb = xyz + (size_t)b * 8192 * 3;
    int* out = idxout + (size_t)wid * K;
    int count = 0;
    int first = 0;
    for (int base = 0; base < 8192 && count < K; base += 64) {
        int j = base + lane;
        float dx = __fsub_rn(xb[j * 3 + 0], qx);
        float dy = __fsub_rn(xb[j * 3 + 1], qy);
        float dz = __fsub_rn(xb[j * 3 + 2], qz);
        float d2 = __fadd_rn(__fadd_rn(__fmul_rn(dx, dx), __fmul_rn(dy, dy)), __fmul_rn(dz, dz));
        bool in = d2 < r2;
        unsigned long long m = __ballot(in);
        if (count == 0 && m) first = base + __ffsll((long long)m) - 1;
        if (in) {
            int pos = count + __popcll(m & ((1ull << lane) - 1ull));
            if (pos < K) out[pos] = j;
        }
        count += __popcll(m);
    }
    if (count < K) {
        int fillv = (count > 0) ? first : 0;
        for (int p = count + lane; p < K; p += 64) out[p] = fillv;
    }
}

// ---------------- MFMA GEMM ----------------------------------------------------
// Y[M][NCOL] = W[Mp][Kp] * X[Kp][NCOL];  X stored transposed: X^T[col][k] bf16.
// Block: 4 waves, full Mp x 64 cols. Wave w: rows [w*Mp/4, +Mp/4), 4 n-tiles.
// A-frag: lane = W[rbase+mt*16+(lane&15)][ks*32+quad*8 ..+8]      (16B, in VGPRs)
// B-frag: lane = X^T[col0+nt*16+(lane&15)][ks*32+quad*8 ..+8]     (16B contiguous)
// D: row=quad*4+r, col=lane&15 -> store 4 consecutive m = 8B into next X^T.
// IN_MODE 0: B from featTp[idx[col]] (+rel-xyz patch on quad0/ks0). No affine.
// IN_MODE 1: affine+relu (prev layer BN) applied on B-frag load.
// OUT_MODE 0: store Y^T bf16.  OUT_MODE 1: fused max/min over K-sample groups.
// Both: per-channel sum/sumsq -> width-16 shuffle -> 128-slot spread atomics.
template <int Mp, int Kp, int IN_MODE, int OUT_MODE, int KSH>
__global__ __launch_bounds__(256) void gemm_mfma(
    const unsigned short* __restrict__ Wb, const unsigned short* __restrict__ Xin,
    const float* __restrict__ aff, const int* __restrict__ idx,
    const unsigned short* __restrict__ ftp, const float* __restrict__ newxyz,
    unsigned short* __restrict__ Yout, float* __restrict__ MX, float* __restrict__ MN,
    float* __restrict__ statS, float* __restrict__ statQ) {
    constexpr int MT = Mp / 64;   // m-tiles per wave
    constexpr int KS = Kp / 32;   // K-steps
    const int tid = threadIdx.x;
    const int w = tid >> 6;
    const int lane = tid & 63;
    const int n = lane & 15;
    const int quad = lane >> 4;
    const int rbase = w * (Mp / 4);
    const long col0 = (long)blockIdx.x * 64;

    // A-frags (held in VGPRs for the whole kernel)
    short8 a[MT][KS];
#pragma unroll
    for (int mt = 0; mt < MT; ++mt)
#pragma unroll
        for (int ks = 0; ks < KS; ++ks)
            a[mt][ks] = *(const short8*)(Wb + (size_t)(rbase + mt * 16 + n) * Kp + ks * 32 + quad * 8);

    f32x4 acc[MT][4];
#pragma unroll
    for (int mt = 0; mt < MT; ++mt)
#pragma unroll
        for (int nt = 0; nt < 4; ++nt)
#pragma unroll
            for (int r = 0; r < 4; ++r) acc[mt][nt][r] = 0.f;

    long fbase[4];
    float qv0[4], qv1[4], qv2[4];
    if constexpr (IN_MODE == 0) {
        int bb = (int)(col0 >> (KSH + 10));
#pragma unroll
        for (int nt = 0; nt < 4; ++nt) {
            long col = col0 + nt * 16 + n;
            int j = idx[col];
            fbase[nt] = ((long)bb * 8192 + j) * 96;
            long sk = col >> KSH;  // lane-uniform within nt (16 < 32 <= K)
            qv0[nt] = newxyz[sk * 3 + 0];
            qv1[nt] = newxyz[sk * 3 + 1];
            qv2[nt] = newxyz[sk * 3 + 2];
        }
    }

#pragma unroll
    for (int ks = 0; ks < KS; ++ks) {
        float sc[8], sh[8];
        if constexpr (IN_MODE == 1) {
#pragma unroll
            for (int e = 0; e < 8; ++e) {
                sc[e] = aff[ks * 32 + quad * 8 + e];
                sh[e] = aff[Kp + ks * 32 + quad * 8 + e];
            }
        }
#pragma unroll
        for (int nt = 0; nt < 4; ++nt) {
            short8 bfr;
            if constexpr (IN_MODE == 0) {
                bfr = *(const short8*)(ftp + fbase[nt] + ks * 32 + quad * 8);
                if (ks == 0 && quad == 0) {  // rel-xyz patch: channels 0..2
                    bfr[0] = (short)f2bf(bf2f((unsigned short)bfr[0]) - qv0[nt]);
                    bfr[1] = (short)f2bf(bf2f((unsigned short)bfr[1]) - qv1[nt]);
                    bfr[2] = (short)f2bf(bf2f((unsigned short)bfr[2]) - qv2[nt]);
                }
            } else {
                long col = col0 + nt * 16 + n;
                short8 raw = *(const short8*)(Xin + col * Kp + ks * 32 + quad * 8);
#pragma unroll
                for (int e = 0; e < 8; ++e) {
                    float xf = bf2f((unsigned short)raw[e]);
                    xf = fmaxf(fmaf(xf, sc[e], sh[e]), 0.f);
                    bfr[e] = (short)f2bf(xf);
                }
            }
#pragma unroll
            for (int mt = 0; mt < MT; ++mt)
                acc[mt][nt] = __builtin_amdgcn_mfma_f32_16x16x32_bf16(a[mt][ks], bfr, acc[mt][nt], 0, 0, 0);
        }
    }

    // ---- stats: per-channel sum / sumsq ----
    const int slot = (int)(blockIdx.x & 127);
#pragma unroll
    for (int mt = 0; mt < MT; ++mt)
#pragma unroll
        for (int r = 0; r < 4; ++r) {
            float s = 0.f, q = 0.f;
#pragma unroll
            for (int nt = 0; nt < 4; ++nt) {
                float v = acc[mt][nt][r];
                s += v;
                q = fmaf(v, v, q);
            }
#pragma unroll
            for (int off = 1; off < 16; off <<= 1) {
                s += __shfl_xor(s, off, 16);
                q += __shfl_xor(q, off, 16);
            }
            if (n == 0) {
                int ch = rbase + mt * 16 + quad * 4 + r;
                atomicAdd(statS + (size_t)ch * 128 + slot, s);
                atomicAdd(statQ + (size_t)ch * 128 + slot, q);
            }
        }

    if constexpr (OUT_MODE == 0) {
#pragma unroll
        for (int mt = 0; mt < MT; ++mt)
#pragma unroll
            for (int nt = 0; nt < 4; ++nt) {
                long col = col0 + nt * 16 + n;
                unsigned p0 = f2bf(acc[mt][nt][0]) | ((unsigned)f2bf(acc[mt][nt][1]) << 16);
                unsigned p1 = f2bf(acc[mt][nt][2]) | ((unsigned)f2bf(acc[mt][nt][3]) << 16);
                uint2 st; st.x = p0; st.y = p1;
                *(uint2*)(Yout + col * Mp + rbase + mt * 16 + quad * 4) = st;
            }
    } else {
#pragma unroll
        for (int mt = 0; mt < MT; ++mt)
#pragma unroll
            for (int r = 0; r < 4; ++r) {
                if constexpr (KSH == 6) {  // one group of 64 cols
                    float mx = acc[mt][0][r], mn = acc[mt][0][r];
#pragma unroll
                    for (int nt = 1; nt < 4; ++nt) {
                        mx = fmaxf(mx, acc[mt][nt][r]);
                        mn = fminf(mn, acc[mt][nt][r]);
                    }
#pragma unroll
                    for (int off = 1; off < 16; off <<= 1) {
                        mx = fmaxf(mx, __shfl_xor(mx, off, 16));
                        mn = fminf(mn, __shfl_xor(mn, off, 16));
                    }
                    if (n == 0) {
                        int ch = rbase + mt * 16 + quad * 4 + r;
                        long g = col0 >> 6;
                        MX[(long)ch * 8192 + g] = mx;
                        MN[(long)ch * 8192 + g] = mn;
                    }
                } else {  // two groups of 32 cols
#pragma unroll
                    for (int gh = 0; gh < 2; ++gh) {
                        float mx = fmaxf(acc[mt][2 * gh][r], acc[mt][2 * gh + 1][r]);
                        float mn = fminf(acc[mt][2 * gh][r], acc[mt][2 * gh + 1][r]);
#pragma unroll
                        for (int off = 1; off < 16; off <<= 1) {
                            mx = fmaxf(mx, __shfl_xor(mx, off, 16));
                            mn = fminf(mn, __shfl_xor(mn, off, 16));
                        }
                        if (n == 0) {
                            int ch = rbase + mt * 16 + quad * 4 + r;
                            long g = (col0 >> 5) + gh;
                            MX[(long)ch * 8192 + g] = mx;
                            MN[(long)ch * 8192 + g] = mn;
                        }
                    }
                }
            }
    }
}

// ---------------- finalize BN constants ----------------------------------------
__global__ void finalize_kernel(const float* __restrict__ sS, const float* __restrict__ sQ,
                                const float* __restrict__ g, const float* __restrict__ b,
                                float* __restrict__ aff, int C, float invCount) {
    int c = threadIdx.x + blockIdx.x * blockDim.x;
    if (c >= C) return;
    float s = 0.f, q = 0.f;
    for (int k = 0; k < 128; ++k) { s += sS[c * 128 + k]; q += sQ[c * 128 + k]; }
    float mean = s * invCount;
    float var = fmaxf(q * invCount - mean * mean, 0.f);
    float sc = g[c] / sqrtf(var + 1e-5f);
    float sh = b[c] - mean * sc;
    aff[c] = sc;
    aff[C + c] = sh;
}

// ---------------- final output -------------------------------------------------
__global__ void final_out_kernel(const float* __restrict__ MX, const float* __restrict__ MN,
                                 const float* __restrict__ aff, float* __restrict__ out1,
                                 int Cout, int cOff) {
    long i = (long)blockIdx.x * 256 + threadIdx.x;
    int c = (int)(i >> 13);
    int gidx = (int)(i & 8191);
    int b = gidx >> 10, s = gidx & 1023;
    float sc = aff[c], sh = aff[Cout + c];
    float v = fmaxf(fmaxf(sc * MX[i] + sh, sc * MN[i] + sh), 0.f);
    out1[((long)b * 384 + cOff + c) * 1024 + s] = v;
}

// ---------------- host ---------------------------------------------------------
extern "C" void kernel_launch(void* const* d_in, const int* in_sizes, int n_in,
                              void* d_out, int out_size, void* d_ws, size_t ws_size,
                              hipStream_t stream) {
    const float* xyz = (const float*)d_in[0];
    const float* feat = (const float*)d_in[1];
    const float *W[6], *G[6], *Bi[6];
    for (int l = 0; l < 6; ++l) {
        W[l] = (const float*)d_in[2 + l * 3];
        G[l] = (const float*)d_in[3 + l * 3];
        Bi[l] = (const float*)d_in[4 + l * 3];
    }
    char* ws = (char*)d_ws;
    float* out0 = (float*)d_out;
    float* out1 = (float*)d_out + 24576;

    unsigned short* wb = (unsigned short*)(ws + OFF_WBF);
    float* stats = (float*)(ws + OFF_STATS);
    float* affine = (float*)(ws + OFF_AFF);
    int* idx0 = (int*)(ws + OFF_IDX0);
    int* idx1 = (int*)(ws + OFF_IDX1);
    float* mx = (float*)(ws + OFF_MX);
    float* mn = (float*)(ws + OFF_MN);
    unsigned short* y0 = (unsigned short*)(ws + OFF_Y0);
    unsigned short* y1 = (unsigned short*)(ws + OFF_Y1);
    unsigned short* ftp = (unsigned short*)(ws + OFF_FEATT);

    hipMemsetAsync(stats, 0, STATS_BYTES, stream);
    prep_wbf<<<256, 256, 0, stream>>>(W[0], W[1], W[2], W[3], W[4], W[5], wb);
    feat_transpose<<<dim3(128, 8), 256, 0, stream>>>(xyz, feat, ftp);
    fps_kernel<<<8, 512, 0, stream>>>(xyz, out0);

    // packed-weight offsets (elements)
    const int wOff[6] = {0, 6144, 10240, 18432, 24576, 32768};
    int stOff[6], afOff[6];
    {
        const int Cs[6] = {64, 64, 128, 64, 128, 256};
        int so = 0, ao = 0;
        for (int l = 0; l < 6; ++l) {
            stOff[l] = so; so += Cs[l] * 256;
            afOff[l] = ao; ao += Cs[l] * 2;
        }
    }

    for (int br = 0; br < 2; ++br) {
        const int K = br ? 64 : 32;
        const float radius = br ? 0.8f : 0.4f;
        const long NCOL = 8L * 1024 * K;
        int* idx = br ? idx1 : idx0;
        const int l0 = br * 3, l1 = br * 3 + 1, l2 = br * 3 + 2;
        const int M2 = br ? 256 : 128;
        const float invCount = 1.f / (float)NCOL;
        const int nblk = (int)(NCOL / 64);

        ball_query_kernel<<<2048, 256, 0, stream>>>(xyz, out0, idx, radius * radius, K);

        if (br == 0) {
            gemm_mfma<64, 96, 0, 0, 5><<<nblk, 256, 0, stream>>>(
                wb + wOff[l0], nullptr, nullptr, idx, ftp, out0, y0, nullptr, nullptr,
                stats + stOff[l0], stats + stOff[l0] + 64 * 128);
            finalize_kernel<<<1, 256, 0, stream>>>(stats + stOff[l0], stats + stOff[l0] + 64 * 128,
                                                   G[l0], Bi[l0], affine + afOff[l0], 64, invCount);
            gemm_mfma<64, 64, 1, 0, 5><<<nblk, 256, 0, stream>>>(
                wb + wOff[l1], y0, affine + afOff[l0], nullptr, nullptr, nullptr, y1, nullptr,
                nullptr, stats + stOff[l1], stats + stOff[l1] + 64 * 128);
            finalize_kernel<<<1, 256, 0, stream>>>(stats + stOff[l1], stats + stOff[l1] + 64 * 128,
                                                   G[l1], Bi[l1], affine + afOff[l1], 64, invCount);
            gemm_mfma<128, 64, 1, 1, 5><<<nblk, 256, 0, stream>>>(
                wb + wOff[l2], y1, affine + afOff[l1], nullptr, nullptr, nullptr, nullptr, mx, mn,
                stats + stOff[l2], stats + stOff[l2] + 128 * 128);
            finalize_kernel<<<1, 256, 0, stream>>>(stats + stOff[l2], stats + stOff[l2] + 128 * 128,
                                                   G[l2], Bi[l2], affine + afOff[l2], 128, invCount);
        } else {
            gemm_mfma<64, 96, 0, 0, 6><<<nblk, 256, 0, stream>>>(
                wb + wOff[l0], nullptr, nullptr, idx, ftp, out0, y0, nullptr, nullptr,
                stats + stOff[l0], stats + stOff[l0] + 64 * 128);
            finalize_kernel<<<1, 256, 0, stream>>>(stats + stOff[l0], stats + stOff[l0] + 64 * 128,
                                                   G[l0], Bi[l0], affine + afOff[l0], 64, invCount);
            gemm_mfma<128, 64, 1, 0, 6><<<nblk, 256, 0, stream>>>(
                wb + wOff[l1], y0, affine + afOff[l0], nullptr, nullptr, nullptr, y1, nullptr,
                nullptr, stats + stOff[l1], stats + stOff[l1] + 128 * 128);
            finalize_kernel<<<1, 256, 0, stream>>>(stats + stOff[l1], stats + stOff[l1] + 128 * 128,
                                                   G[l1], Bi[l1], affine + afOff[l1], 128, invCount);
            gemm_mfma<256, 128, 1, 1, 6><<<nblk, 256, 0, stream>>>(
                wb + wOff[l2], y1, affine + afOff[l1], nullptr, nullptr, nullptr, nullptr, mx, mn,
                stats + stOff[l2], stats + stOff[l2] + 256 * 128);
            finalize_kernel<<<1, 256, 0, stream>>>(stats + stOff[l2], stats + stOff[l2] + 256 * 128,
                                                   G[l2], Bi[l2], affine + afOff[l2], 256, invCount);
        }

        final_out_kernel<<<(M2 * 8192) / 256, 256, 0, stream>>>(mx, mn, affine + afOff[l2], out1,
                                                                M2, br ? 128 : 0);
    }
}

// Round 4
// 1792.212 us; speedup vs baseline: 1.6720x; 1.0631x over previous
//
#include <hip/hip_runtime.h>
#include <hip/hip_bf16.h>
#include <cstdint>

// B=8, N=8192, S=1024, C=64
// branch0: r=0.4, K=32, layers 64x67, 64x64, 128x64
// branch1: r=0.8, K=64, layers 64x67, 128x64, 256x128

typedef __attribute__((ext_vector_type(8))) short short8;
typedef __attribute__((ext_vector_type(4))) float f32x4;

__device__ __forceinline__ float bf2f(unsigned short u) {
    return __uint_as_float(((unsigned)u) << 16);
}
__device__ __forceinline__ unsigned short f2bf(float f) {
    unsigned u = __float_as_uint(f);
    return (unsigned short)((u + 0x7fffu + ((u >> 16) & 1u)) >> 16);  // RNE
}

// Wave-64 reductions on the VALU pipe via DPP (rocPRIM pattern): result in lane 63.
// row_shr1/2/4/8 then row_bcast15, row_bcast31. Invalid source lanes keep `old`
// (identity), bound_ctrl=false, row/bank masks full.
__device__ __forceinline__ float wave_red_max_f32(float v) {
#define DPPSTEP(ctrl)                                                                  \
    {                                                                                  \
        int _t = __builtin_amdgcn_update_dpp((int)0xFF800000, __float_as_int(v), ctrl, \
                                             0xf, 0xf, false);                         \
        v = fmaxf(v, __int_as_float(_t));                                              \
    }
    DPPSTEP(0x111) DPPSTEP(0x112) DPPSTEP(0x114) DPPSTEP(0x118) DPPSTEP(0x142) DPPSTEP(0x143)
#undef DPPSTEP
    return v;
}
__device__ __forceinline__ unsigned wave_red_min_u32(unsigned v) {
#define DPPSTEP(ctrl)                                                                   \
    {                                                                                   \
        unsigned _t = (unsigned)__builtin_amdgcn_update_dpp((int)0xFFFFFFFF, (int)v,    \
                                                            ctrl, 0xf, 0xf, false);     \
        v = v < _t ? v : _t;                                                            \
    }
    DPPSTEP(0x111) DPPSTEP(0x112) DPPSTEP(0x114) DPPSTEP(0x118) DPPSTEP(0x142) DPPSTEP(0x143)
#undef DPPSTEP
    return v;
}

// ---------------- workspace layout (bytes); peak = 224,395,264 ------------------
static const size_t OFF_WBF   = 0;          // packed bf16 weights, 65536 elems (128 KB)
static const size_t OFF_STATS = 262144;     // 704 ch * 128 slots * 2 * 4B
static const size_t STATS_BYTES = 720896;
static const size_t OFF_AFF   = 1048576;    // per-layer scale/shift
static const size_t OFF_IDX0  = 2097152;    // 8*1024*32 ints
static const size_t OFF_IDX1  = 3145728;    // 8*1024*64 ints
static const size_t OFF_MX    = 5242880;    // 256*8192 fp32
static const size_t OFF_MN    = 13631488;
static const size_t OFF_Y0    = 22020096;   // bf16 X^T [NCOL][64]  (max 67 MB)
static const size_t OFF_Y1    = 90177536;   // bf16 X^T [NCOL][128] (max 134 MB)
static const size_t OFF_FEATT = 211812352;  // bf16 [8*8192][96] = 12.58 MB, overlaps Y1 tail:
// featTp written before branches, last read in br1-L0; Y1 bytes beyond 121.6 MB are only
// written by br1-L1 which runs after br1-L0. br0 uses only the first 33.5 MB of Y1.

// ---------------- weight pack: w[M][K] f32 -> wb[Mp][Kp] bf16 (zero pad) --------
__global__ void prep_wbf(const float* __restrict__ w0, const float* __restrict__ w1,
                         const float* __restrict__ w2, const float* __restrict__ w3,
                         const float* __restrict__ w4, const float* __restrict__ w5,
                         unsigned short* __restrict__ wb) {
    int id = blockIdx.x * 256 + threadIdx.x;  // 0..65535
    const int psz[6] = {6144, 4096, 8192, 6144, 8192, 32768};
    const int Kp[6] = {96, 64, 64, 96, 64, 128};
    const int Ks[6] = {67, 64, 64, 67, 64, 128};
    const float* wp[6] = {w0, w1, w2, w3, w4, w5};
    int off = 0;
    for (int l = 0; l < 6; ++l) {
        if (id < off + psz[l]) {
            int e = id - off;
            int m = e / Kp[l], k = e - m * Kp[l];
            float v = (k < Ks[l]) ? wp[l][m * Ks[l] + k] : 0.f;
            wb[id] = f2bf(v);
            return;
        }
        off += psz[l];
    }
}

// ---------------- featTp: [8][8192][96] bf16; c0..2 = xyz, c3..66 = feat, rest 0 --
__global__ __launch_bounds__(256) void feat_transpose(const float* __restrict__ xyz,
                                                      const float* __restrict__ feat,
                                                      unsigned short* __restrict__ ft) {
    __shared__ float tile[64][65];
    const int b = blockIdx.y;
    const int j0 = blockIdx.x * 64;
    const int tid = threadIdx.x;
#pragma unroll
    for (int i = 0; i < 16; ++i) {
        int e = i * 256 + tid;
        int c = e >> 6, j = e & 63;
        tile[j][c] = feat[((size_t)b * 64 + c) * 8192 + j0 + j];
    }
    __syncthreads();
#pragma unroll
    for (int i = 0; i < 16; ++i) {
        int e = i * 256 + tid;
        int j = e >> 6, c = e & 63;
        ft[((size_t)(b * 8192 + j0 + j)) * 96 + 3 + c] = f2bf(tile[j][c]);
    }
    // xyz channels + zero pad
    if (tid < 64) {
        int j = tid;
        size_t base = ((size_t)(b * 8192 + j0 + j)) * 96;
        const float* xp = xyz + ((size_t)b * 8192 + j0 + j) * 3;
        ft[base + 0] = f2bf(xp[0]);
        ft[base + 1] = f2bf(xp[1]);
        ft[base + 2] = f2bf(xp[2]);
    } else if (tid < 128) {
        int j = tid - 64;
        size_t base = ((size_t)(b * 8192 + j0 + j)) * 96;
        for (int c = 67; c < 96; ++c) ft[base + c] = 0;
    }
}

// ---------------- FPS: one block (512 threads, 8 waves) per batch ----------------
// All 8193 pts in LDS. Per iter: dist update (register-resident points) ->
// wave f32 max via DPP (VALU pipe, ~50 cyc vs ~500 for ds_swizzle cascade) ->
// readlane broadcast -> per-thread register scan recovers first-occurrence index ->
// wave u32 min via DPP -> one barrier -> all lanes broadcast-read 8 packed u64 keys
// -> 7 VALU compares -> centroid LDS read. Trajectory bit-identical to v2/v3.
__global__ __launch_bounds__(512) void fps_kernel(const float* __restrict__ xyz,
                                                  float* __restrict__ newxyz) {
    const int b = blockIdx.x;
    const int t = threadIdx.x;
    const int lane = t & 63, wv = t >> 6;
    const float* xb = xyz + (size_t)b * 8192 * 3;

    __shared__ float ptsx[8200];
    __shared__ float ptsy[8200];
    __shared__ float ptsz[8200];
    __shared__ float ldsM[16][3];
    __shared__ float meanv[3];
    __shared__ alignas(16) unsigned long long sKey[2][8];

    float px[16], py[16], pz[16], d[16];
#pragma unroll
    for (int j = 0; j < 16; ++j) {
        int q = t + 512 * j;
        px[j] = xb[q * 3 + 0];
        py[j] = xb[q * 3 + 1];
        pz[j] = xb[q * 3 + 2];
        d[j] = 1e10f;
        ptsx[q + 1] = px[j];
        ptsy[q + 1] = py[j];
        ptsz[q + 1] = pz[j];
    }
    // ---- mean: bit-identical replication of the v1 1024-partial tree ----
    float sxA = 0.f, syA = 0.f, szA = 0.f;
    float sxB = 0.f, syB = 0.f, szB = 0.f;
    int uA = (t + 1023) & 1023;
    int uB = (t + 511) & 1023;
#pragma unroll
    for (int j = 0; j < 8; ++j) {
        int ia = uA + 1024 * j;
        int ib = uB + 1024 * j;
        sxA += xb[ia * 3 + 0]; syA += xb[ia * 3 + 1]; szA += xb[ia * 3 + 2];
        sxB += xb[ib * 3 + 0]; syB += xb[ib * 3 + 1]; szB += xb[ib * 3 + 2];
    }
#pragma unroll
    for (int off = 32; off; off >>= 1) {
        sxA += __shfl_xor(sxA, off, 64);
        syA += __shfl_xor(syA, off, 64);
        szA += __shfl_xor(szA, off, 64);
        sxB += __shfl_xor(sxB, off, 64);
        syB += __shfl_xor(syB, off, 64);
        szB += __shfl_xor(szB, off, 64);
    }
    if (lane == 0) {
        ldsM[wv][0] = sxA; ldsM[wv][1] = syA; ldsM[wv][2] = szA;
        ldsM[wv + 8][0] = sxB; ldsM[wv + 8][1] = syB; ldsM[wv + 8][2] = szB;
    }
    __syncthreads();
    if (t < 3) {
        float s = 0.f;
        for (int w = 0; w < 16; ++w) s += ldsM[w][t];
        meanv[t] = s * (1.f / 8192.f);
    }
    __syncthreads();
    float cx = meanv[0], cy = meanv[1], cz = meanv[2];
    const float mmx = cx, mmy = cy, mmz = cz;  // mean point (pts idx 0), owned by t0
    float dm = 1e10f;
    if (t == 0) { ptsx[0] = cx; ptsy[0] = cy; ptsz[0] = cz; }
    __syncthreads();

    for (int it = 0; it < 1024; ++it) {
        if (t == 0) {
            float* o = newxyz + ((size_t)b * 1024 + it) * 3;
            o[0] = cx; o[1] = cy; o[2] = cz;
        }
        float vmax = -1e30f;
#pragma unroll
        for (int j = 0; j < 16; ++j) {
            // no-fma ordering, identical to v1/v2/v3 (tracks the XLA reference)
            float dx = __fsub_rn(px[j], cx);
            float dy = __fsub_rn(py[j], cy);
            float dz = __fsub_rn(pz[j], cz);
            float dd = __fadd_rn(__fadd_rn(__fmul_rn(dx, dx), __fmul_rn(dy, dy)), __fmul_rn(dz, dz));
            float nd = fminf(d[j], dd);
            d[j] = nd;
            vmax = fmaxf(vmax, nd);
        }
        if (t == 0) {
            float dx = __fsub_rn(mmx, cx);
            float dy = __fsub_rn(mmy, cy);
            float dz = __fsub_rn(mmz, cz);
            float dd = __fadd_rn(__fadd_rn(__fmul_rn(dx, dx), __fmul_rn(dy, dy)), __fmul_rn(dz, dz));
            dm = fminf(dm, dd);
            vmax = fmaxf(vmax, dm);
        }
        // wave max value (DPP, VALU pipe) -> uniform broadcast
        float wm = wave_red_max_f32(vmax);
        float bmaxw = __int_as_float(__builtin_amdgcn_readlane(__float_as_int(wm), 63));
        // first-occurrence index among this wave's ties: scan registers, j descending
        unsigned mi = 0xFFFFFFFFu;
#pragma unroll
        for (int j = 15; j >= 0; --j) mi = (d[j] == bmaxw) ? (unsigned)(t + 512 * j + 1) : mi;
        if (t == 0 && dm == bmaxw) mi = 0u;
        unsigned wmin = wave_red_min_u32(mi);
        unsigned miw = (unsigned)__builtin_amdgcn_readlane((int)wmin, 63);
        int par = it & 1;
        if (lane == 0)
            sKey[par][wv] = ((unsigned long long)__float_as_uint(bmaxw) << 32) |
                            (unsigned long long)(8192u - miw);
        __syncthreads();  // the ONLY barrier per iteration (parity-double-buffered slots)
        unsigned long long k = sKey[par][0];
#pragma unroll
        for (int i = 1; i < 8; ++i) {
            unsigned long long o = sKey[par][i];  // same-address broadcast reads
            if (o > k) k = o;
        }
        int far = 8192 - (int)(unsigned)(k & 0xffffffffull);
        cx = ptsx[far];  // uniform LDS broadcast
        cy = ptsy[far];
        cz = ptsz[far];
    }
}

// ---------------- ball query (unchanged) ---------------------------------------
__global__ void ball_query_kernel(const float* __restrict__ xyz, const float* __restrict__ newxyz,
                                  int* __restrict__ idxout, float r2, int K) {
    int wid = (blockIdx.x * blockDim.x + threadIdx.x) >> 6;
    int lane = threadIdx.x & 63;
    int b = wid >> 10;
    const float* q = newxyz + (size_t)wid * 3;
    float qx = q[0], qy = q[1], qz = q[2];
    const float* xb = xyz + (size_t)b * 8192 * 3;
    int* out = idxout + (size_t)wid * K;
    int count = 0;
    int first = 0;
    for (int base = 0; base < 8192 && count < K; base += 64) {
        int j = base + lane;
        float dx = __fsub_rn(xb[j * 3 + 0], qx);
        float dy = __fsub_rn(xb[j * 3 + 1], qy);
        float dz = __fsub_rn(xb[j * 3 + 2], qz);
        float d2 = __fadd_rn(__fadd_rn(__fmul_rn(dx, dx), __fmul_rn(dy, dy)), __fmul_rn(dz, dz));
        bool in = d2 < r2;
        unsigned long long m = __ballot(in);
        if (count == 0 && m) first = base + __ffsll((long long)m) - 1;
        if (in) {
            int pos = count + __popcll(m & ((1ull << lane) - 1ull));
            if (pos < K) out[pos] = j;
        }
        count += __popcll(m);
    }
    if (count < K) {
        int fillv = (count > 0) ? first : 0;
        for (int p = count + lane; p < K; p += 64) out[p] = fillv;
    }
}

// ---------------- MFMA GEMM (unchanged from v3) --------------------------------
template <int Mp, int Kp, int IN_MODE, int OUT_MODE, int KSH>
__global__ __launch_bounds__(256) void gemm_mfma(
    const unsigned short* __restrict__ Wb, const unsigned short* __restrict__ Xin,
    const float* __restrict__ aff, const int* __restrict__ idx,
    const unsigned short* __restrict__ ftp, const float* __restrict__ newxyz,
    unsigned short* __restrict__ Yout, float* __restrict__ MX, float* __restrict__ MN,
    float* __restrict__ statS, float* __restrict__ statQ) {
    constexpr int MT = Mp / 64;   // m-tiles per wave
    constexpr int KS = Kp / 32;   // K-steps
    const int tid = threadIdx.x;
    const int w = tid >> 6;
    const int lane = tid & 63;
    const int n = lane & 15;
    const int quad = lane >> 4;
    const int rbase = w * (Mp / 4);
    const long col0 = (long)blockIdx.x * 64;

    short8 a[MT][KS];
#pragma unroll
    for (int mt = 0; mt < MT; ++mt)
#pragma unroll
        for (int ks = 0; ks < KS; ++ks)
            a[mt][ks] = *(const short8*)(Wb + (size_t)(rbase + mt * 16 + n) * Kp + ks * 32 + quad * 8);

    f32x4 acc[MT][4];
#pragma unroll
    for (int mt = 0; mt < MT; ++mt)
#pragma unroll
        for (int nt = 0; nt < 4; ++nt)
#pragma unroll
            for (int r = 0; r < 4; ++r) acc[mt][nt][r] = 0.f;

    long fbase[4];
    float qv0[4], qv1[4], qv2[4];
    if constexpr (IN_MODE == 0) {
        int bb = (int)(col0 >> (KSH + 10));
#pragma unroll
        for (int nt = 0; nt < 4; ++nt) {
            long col = col0 + nt * 16 + n;
            int j = idx[col];
            fbase[nt] = ((long)bb * 8192 + j) * 96;
            long sk = col >> KSH;
            qv0[nt] = newxyz[sk * 3 + 0];
            qv1[nt] = newxyz[sk * 3 + 1];
            qv2[nt] = newxyz[sk * 3 + 2];
        }
    }

#pragma unroll
    for (int ks = 0; ks < KS; ++ks) {
        float sc[8], sh[8];
        if constexpr (IN_MODE == 1) {
#pragma unroll
            for (int e = 0; e < 8; ++e) {
                sc[e] = aff[ks * 32 + quad * 8 + e];
                sh[e] = aff[Kp + ks * 32 + quad * 8 + e];
            }
        }
#pragma unroll
        for (int nt = 0; nt < 4; ++nt) {
            short8 bfr;
            if constexpr (IN_MODE == 0) {
                bfr = *(const short8*)(ftp + fbase[nt] + ks * 32 + quad * 8);
                if (ks == 0 && quad == 0) {
                    bfr[0] = (short)f2bf(bf2f((unsigned short)bfr[0]) - qv0[nt]);
                    bfr[1] = (short)f2bf(bf2f((unsigned short)bfr[1]) - qv1[nt]);
                    bfr[2] = (short)f2bf(bf2f((unsigned short)bfr[2]) - qv2[nt]);
                }
            } else {
                long col = col0 + nt * 16 + n;
                short8 raw = *(const short8*)(Xin + col * Kp + ks * 32 + quad * 8);
#pragma unroll
                for (int e = 0; e < 8; ++e) {
                    float xf = bf2f((unsigned short)raw[e]);
                    xf = fmaxf(fmaf(xf, sc[e], sh[e]), 0.f);
                    bfr[e] = (short)f2bf(xf);
                }
            }
#pragma unroll
            for (int mt = 0; mt < MT; ++mt)
                acc[mt][nt] = __builtin_amdgcn_mfma_f32_16x16x32_bf16(a[mt][ks], bfr, acc[mt][nt], 0, 0, 0);
        }
    }

    const int slot = (int)(blockIdx.x & 127);
#pragma unroll
    for (int mt = 0; mt < MT; ++mt)
#pragma unroll
        for (int r = 0; r < 4; ++r) {
            float s = 0.f, q = 0.f;
#pragma unroll
            for (int nt = 0; nt < 4; ++nt) {
                float v = acc[mt][nt][r];
                s += v;
                q = fmaf(v, v, q);
            }
#pragma unroll
            for (int off = 1; off < 16; off <<= 1) {
                s += __shfl_xor(s, off, 16);
                q += __shfl_xor(q, off, 16);
            }
            if (n == 0) {
                int ch = rbase + mt * 16 + quad * 4 + r;
                atomicAdd(statS + (size_t)ch * 128 + slot, s);
                atomicAdd(statQ + (size_t)ch * 128 + slot, q);
            }
        }

    if constexpr (OUT_MODE == 0) {
#pragma unroll
        for (int mt = 0; mt < MT; ++mt)
#pragma unroll
            for (int nt = 0; nt < 4; ++nt) {
                long col = col0 + nt * 16 + n;
                unsigned p0 = f2bf(acc[mt][nt][0]) | ((unsigned)f2bf(acc[mt][nt][1]) << 16);
                unsigned p1 = f2bf(acc[mt][nt][2]) | ((unsigned)f2bf(acc[mt][nt][3]) << 16);
                uint2 st; st.x = p0; st.y = p1;
                *(uint2*)(Yout + col * Mp + rbase + mt * 16 + quad * 4) = st;
            }
    } else {
#pragma unroll
        for (int mt = 0; mt < MT; ++mt)
#pragma unroll
            for (int r = 0; r < 4; ++r) {
                if constexpr (KSH == 6) {
                    float mx = acc[mt][0][r], mn = acc[mt][0][r];
#pragma unroll
                    for (int nt = 1; nt < 4; ++nt) {
                        mx = fmaxf(mx, acc[mt][nt][r]);
                        mn = fminf(mn, acc[mt][nt][r]);
                    }
#pragma unroll
                    for (int off = 1; off < 16; off <<= 1) {
                        mx = fmaxf(mx, __shfl_xor(mx, off, 16));
                        mn = fminf(mn, __shfl_xor(mn, off, 16));
                    }
                    if (n == 0) {
                        int ch = rbase + mt * 16 + quad * 4 + r;
                        long g = col0 >> 6;
                        MX[(long)ch * 8192 + g] = mx;
                        MN[(long)ch * 8192 + g] = mn;
                    }
                } else {
#pragma unroll
                    for (int gh = 0; gh < 2; ++gh) {
                        float mx = fmaxf(acc[mt][2 * gh][r], acc[mt][2 * gh + 1][r]);
                        float mn = fminf(acc[mt][2 * gh][r], acc[mt][2 * gh + 1][r]);
#pragma unroll
                        for (int off = 1; off < 16; off <<= 1) {
                            mx = fmaxf(mx, __shfl_xor(mx, off, 16));
                            mn = fminf(mn, __shfl_xor(mn, off, 16));
                        }
                        if (n == 0) {
                            int ch = rbase + mt * 16 + quad * 4 + r;
                            long g = (col0 >> 5) + gh;
                            MX[(long)ch * 8192 + g] = mx;
                            MN[(long)ch * 8192 + g] = mn;
                        }
                    }
                }
            }
    }
}

// ---------------- finalize BN constants ----------------------------------------
__global__ void finalize_kernel(const float* __restrict__ sS, const float* __restrict__ sQ,
                                const float* __restrict__ g, const float* __restrict__ b,
                                float* __restrict__ aff, int C, float invCount) {
    int c = threadIdx.x + blockIdx.x * blockDim.x;
    if (c >= C) return;
    float s = 0.f, q = 0.f;
    for (int k = 0; k < 128; ++k) { s += sS[c * 128 + k]; q += sQ[c * 128 + k]; }
    float mean = s * invCount;
    float var = fmaxf(q * invCount - mean * mean, 0.f);
    float sc = g[c] / sqrtf(var + 1e-5f);
    float sh = b[c] - mean * sc;
    aff[c] = sc;
    aff[C + c] = sh;
}

// ---------------- final output -------------------------------------------------
__global__ void final_out_kernel(const float* __restrict__ MX, const float* __restrict__ MN,
                                 const float* __restrict__ aff, float* __restrict__ out1,
                                 int Cout, int cOff) {
    long i = (long)blockIdx.x * 256 + threadIdx.x;
    int c = (int)(i >> 13);
    int gidx = (int)(i & 8191);
    int b = gidx >> 10, s = gidx & 1023;
    float sc = aff[c], sh = aff[Cout + c];
    float v = fmaxf(fmaxf(sc * MX[i] + sh, sc * MN[i] + sh), 0.f);
    out1[((long)b * 384 + cOff + c) * 1024 + s] = v;
}

// ---------------- host ---------------------------------------------------------
extern "C" void kernel_launch(void* const* d_in, const int* in_sizes, int n_in,
                              void* d_out, int out_size, void* d_ws, size_t ws_size,
                              hipStream_t stream) {
    const float* xyz = (const float*)d_in[0];
    const float* feat = (const float*)d_in[1];
    const float *W[6], *G[6], *Bi[6];
    for (int l = 0; l < 6; ++l) {
        W[l] = (const float*)d_in[2 + l * 3];
        G[l] = (const float*)d_in[3 + l * 3];
        Bi[l] = (const float*)d_in[4 + l * 3];
    }
    char* ws = (char*)d_ws;
    float* out0 = (float*)d_out;
    float* out1 = (float*)d_out + 24576;

    unsigned short* wb = (unsigned short*)(ws + OFF_WBF);
    float* stats = (float*)(ws + OFF_STATS);
    float* affine = (float*)(ws + OFF_AFF);
    int* idx0 = (int*)(ws + OFF_IDX0);
    int* idx1 = (int*)(ws + OFF_IDX1);
    float* mx = (float*)(ws + OFF_MX);
    float* mn = (float*)(ws + OFF_MN);
    unsigned short* y0 = (unsigned short*)(ws + OFF_Y0);
    unsigned short* y1 = (unsigned short*)(ws + OFF_Y1);
    unsigned short* ftp = (unsigned short*)(ws + OFF_FEATT);

    hipMemsetAsync(stats, 0, STATS_BYTES, stream);
    prep_wbf<<<256, 256, 0, stream>>>(W[0], W[1], W[2], W[3], W[4], W[5], wb);
    feat_transpose<<<dim3(128, 8), 256, 0, stream>>>(xyz, feat, ftp);
    fps_kernel<<<8, 512, 0, stream>>>(xyz, out0);

    const int wOff[6] = {0, 6144, 10240, 18432, 24576, 32768};
    int stOff[6], afOff[6];
    {
        const int Cs[6] = {64, 64, 128, 64, 128, 256};
        int so = 0, ao = 0;
        for (int l = 0; l < 6; ++l) {
            stOff[l] = so; so += Cs[l] * 256;
            afOff[l] = ao; ao += Cs[l] * 2;
        }
    }

    for (int br = 0; br < 2; ++br) {
        const int K = br ? 64 : 32;
        const float radius = br ? 0.8f : 0.4f;
        const long NCOL = 8L * 1024 * K;
        int* idx = br ? idx1 : idx0;
        const int l0 = br * 3, l1 = br * 3 + 1, l2 = br * 3 + 2;
        const int M2 = br ? 256 : 128;
        const float invCount = 1.f / (float)NCOL;
        const int nblk = (int)(NCOL / 64);

        ball_query_kernel<<<2048, 256, 0, stream>>>(xyz, out0, idx, radius * radius, K);

        if (br == 0) {
            gemm_mfma<64, 96, 0, 0, 5><<<nblk, 256, 0, stream>>>(
                wb + wOff[l0], nullptr, nullptr, idx, ftp, out0, y0, nullptr, nullptr,
                stats + stOff[l0], stats + stOff[l0] + 64 * 128);
            finalize_kernel<<<1, 256, 0, stream>>>(stats + stOff[l0], stats + stOff[l0] + 64 * 128,
                                                   G[l0], Bi[l0], affine + afOff[l0], 64, invCount);
            gemm_mfma<64, 64, 1, 0, 5><<<nblk, 256, 0, stream>>>(
                wb + wOff[l1], y0, affine + afOff[l0], nullptr, nullptr, nullptr, y1, nullptr,
                nullptr, stats + stOff[l1], stats + stOff[l1] + 64 * 128);
            finalize_kernel<<<1, 256, 0, stream>>>(stats + stOff[l1], stats + stOff[l1] + 64 * 128,
                                                   G[l1], Bi[l1], affine + afOff[l1], 64, invCount);
            gemm_mfma<128, 64, 1, 1, 5><<<nblk, 256, 0, stream>>>(
                wb + wOff[l2], y1, affine + afOff[l1], nullptr, nullptr, nullptr, nullptr, mx, mn,
                stats + stOff[l2], stats + stOff[l2] + 128 * 128);
            finalize_kernel<<<1, 256, 0, stream>>>(stats + stOff[l2], stats + stOff[l2] + 128 * 128,
                                                   G[l2], Bi[l2], affine + afOff[l2], 128, invCount);
        } else {
            gemm_mfma<64, 96, 0, 0, 6><<<nblk, 256, 0, stream>>>(
                wb + wOff[l0], nullptr, nullptr, idx, ftp, out0, y0, nullptr, nullptr,
                stats + stOff[l0], stats + stOff[l0] + 64 * 128);
            finalize_kernel<<<1, 256, 0, stream>>>(stats + stOff[l0], stats + stOff[l0] + 64 * 128,
                                                   G[l0], Bi[l0], affine + afOff[l0], 64, invCount);
            gemm_mfma<128, 64, 1, 0, 6><<<nblk, 256, 0, stream>>>(
                wb + wOff[l1], y0, affine + afOff[l0], nullptr, nullptr, nullptr, y1, nullptr,
                nullptr, stats + stOff[l1], stats + stOff[l1] + 128 * 128);
            finalize_kernel<<<1, 256, 0, stream>>>(stats + stOff[l1], stats + stOff[l1] + 128 * 128,
                                                   G[l1], Bi[l1], affine + afOff[l1], 128, invCount);
            gemm_mfma<256, 128, 1, 1, 6><<<nblk, 256, 0, stream>>>(
                wb + wOff[l2], y1, affine + afOff[l1], nullptr, nullptr, nullptr, nullptr, mx, mn,
                stats + stOff[l2], stats + stOff[l2] + 256 * 128);
            finalize_kernel<<<1, 256, 0, stream>>>(stats + stOff[l2], stats + stOff[l2] + 256 * 128,
                                                   G[l2], Bi[l2], affine + afOff[l2], 256, invCount);
        }

        final_out_kernel<<<(M2 * 8192) / 256, 256, 0, stream>>>(mx, mn, affine + afOff[l2], out1,
                                                                M2, br ? 128 : 0);
    }
}

// Round 5
// 1773.033 us; speedup vs baseline: 1.6900x; 1.0108x over previous
//
#include <hip/hip_runtime.h>
#include <hip/hip_bf16.h>
#include <cstdint>

// B=8, N=8192, S=1024, C=64
// branch0: r=0.4, K=32, layers 64x67, 64x64, 128x64
// branch1: r=0.8, K=64, layers 64x67, 128x64, 256x128

typedef __attribute__((ext_vector_type(8))) short short8;
typedef __attribute__((ext_vector_type(4))) float f32x4;
typedef __attribute__((ext_vector_type(2))) float f32x2;

__device__ __forceinline__ float bf2f(unsigned short u) {
    return __uint_as_float(((unsigned)u) << 16);
}
__device__ __forceinline__ unsigned short f2bf(float f) {
    unsigned u = __float_as_uint(f);
    return (unsigned short)((u + 0x7fffu + ((u >> 16) & 1u)) >> 16);  // RNE
}

// Wave-64 reductions on the VALU pipe via DPP (rocPRIM pattern): result in lane 63.
__device__ __forceinline__ float wave_red_max_f32(float v) {
#define DPPSTEP(ctrl)                                                                  \
    {                                                                                  \
        int _t = __builtin_amdgcn_update_dpp((int)0xFF800000, __float_as_int(v), ctrl, \
                                             0xf, 0xf, false);                         \
        v = fmaxf(v, __int_as_float(_t));                                              \
    }
    DPPSTEP(0x111) DPPSTEP(0x112) DPPSTEP(0x114) DPPSTEP(0x118) DPPSTEP(0x142) DPPSTEP(0x143)
#undef DPPSTEP
    return v;
}
__device__ __forceinline__ unsigned wave_red_min_u32(unsigned v) {
#define DPPSTEP(ctrl)                                                                   \
    {                                                                                   \
        unsigned _t = (unsigned)__builtin_amdgcn_update_dpp((int)0xFFFFFFFF, (int)v,    \
                                                            ctrl, 0xf, 0xf, false);     \
        v = v < _t ? v : _t;                                                            \
    }
    DPPSTEP(0x111) DPPSTEP(0x112) DPPSTEP(0x114) DPPSTEP(0x118) DPPSTEP(0x142) DPPSTEP(0x143)
#undef DPPSTEP
    return v;
}
__device__ __forceinline__ unsigned long long u64max(unsigned long long a, unsigned long long b) {
    return a > b ? a : b;
}
__device__ __forceinline__ unsigned u32min(unsigned a, unsigned b) { return a < b ? a : b; }

// ---------------- workspace layout (bytes); peak = 224,395,264 ------------------
static const size_t OFF_WBF   = 0;          // packed bf16 weights, 65536 elems (128 KB)
static const size_t OFF_STATS = 262144;     // 704 ch * 128 slots * 2 * 4B
static const size_t STATS_BYTES = 720896;
static const size_t OFF_AFF   = 1048576;    // per-layer scale/shift
static const size_t OFF_IDX0  = 2097152;    // 8*1024*32 ints
static const size_t OFF_IDX1  = 3145728;    // 8*1024*64 ints
static const size_t OFF_MX    = 5242880;    // 256*8192 fp32
static const size_t OFF_MN    = 13631488;
static const size_t OFF_Y0    = 22020096;   // bf16 X^T [NCOL][64]  (max 67 MB)
static const size_t OFF_Y1    = 90177536;   // bf16 X^T [NCOL][128] (max 134 MB)
static const size_t OFF_FEATT = 211812352;  // bf16 [8*8192][96] = 12.58 MB, overlaps Y1 tail
// (featTp last read in br1-L0; Y1 beyond 121.6 MB only written by br1-L1, which runs later)

// ---------------- fused pre-kernel: FPS (blocks 0..7) + feat transpose (8..1031)
//                  + weight pack (1032..1159), all concurrent on different CUs ----
__global__ __launch_bounds__(512) void fused_pre(
    const float* __restrict__ xyz, const float* __restrict__ feat,
    float* __restrict__ newxyz, unsigned short* __restrict__ ft,
    const float* __restrict__ w0, const float* __restrict__ w1, const float* __restrict__ w2,
    const float* __restrict__ w3, const float* __restrict__ w4, const float* __restrict__ w5,
    unsigned short* __restrict__ wb) {
    __shared__ union alignas(16) SM {
        struct {
            float ptsx[8200], ptsy[8200], ptsz[8200];
            float ldsM[16][3];
            float meanv[3];
            unsigned long long sKey[2][8];
        } f;
        float tile[64][65];
    } sm;
    const int tid = threadIdx.x;

    if (blockIdx.x >= 1032) {
        // ---- weight pack: w[M][K] f32 -> wb[Mp][Kp] bf16 (zero pad) ----
        int id = (int)(blockIdx.x - 1032) * 512 + tid;  // 0..65535
        const int psz[6] = {6144, 4096, 8192, 6144, 8192, 32768};
        const int Kp[6] = {96, 64, 64, 96, 64, 128};
        const int Ks[6] = {67, 64, 64, 67, 64, 128};
        const float* wp[6] = {w0, w1, w2, w3, w4, w5};
        int off = 0;
        for (int l = 0; l < 6; ++l) {
            if (id < off + psz[l]) {
                int e = id - off;
                int m = e / Kp[l], k = e - m * Kp[l];
                float v = (k < Ks[l]) ? wp[l][m * Ks[l] + k] : 0.f;
                wb[id] = f2bf(v);
                return;
            }
            off += psz[l];
        }
        return;
    }

    if (blockIdx.x >= 8) {
        // ---- featTp: [8][8192][96] bf16; c0..2 = xyz, c3..66 = feat, rest 0 ----
        int tb = (int)blockIdx.x - 8;  // 0..1023
        int b = tb >> 7;
        int j0 = (tb & 127) * 64;
#pragma unroll
        for (int i = 0; i < 8; ++i) {
            int e = i * 512 + tid;
            int c = e >> 6, j = e & 63;
            sm.tile[j][c] = feat[((size_t)b * 64 + c) * 8192 + j0 + j];
        }
        __syncthreads();
#pragma unroll
        for (int i = 0; i < 8; ++i) {
            int e = i * 512 + tid;
            int j = e >> 6, c = e & 63;
            ft[((size_t)(b * 8192 + j0 + j)) * 96 + 3 + c] = f2bf(sm.tile[j][c]);
        }
        if (tid < 64) {
            int j = tid;
            size_t base = ((size_t)(b * 8192 + j0 + j)) * 96;
            const float* xp = xyz + ((size_t)b * 8192 + j0 + j) * 3;
            ft[base + 0] = f2bf(xp[0]);
            ft[base + 1] = f2bf(xp[1]);
            ft[base + 2] = f2bf(xp[2]);
        } else if (tid < 128) {
            int j = tid - 64;
            size_t base = ((size_t)(b * 8192 + j0 + j)) * 96;
            for (int c = 67; c < 96; ++c) ft[base + c] = 0;
        }
        return;
    }

    // ---- FPS: 8 waves, 16 pts/thread as 8 float2 pairs (packed-f32 dist math) ----
    const int b = blockIdx.x;
    const int t = tid;
    const int lane = t & 63, wv = t >> 6;
    const float* xb = xyz + (size_t)b * 8192 * 3;

    f32x2 px[8], py[8], pz[8], d[8];
#pragma unroll
    for (int k = 0; k < 8; ++k) {
        int q0 = t + 512 * (2 * k);
        int q1 = t + 512 * (2 * k + 1);
        px[k].x = xb[q0 * 3 + 0]; px[k].y = xb[q1 * 3 + 0];
        py[k].x = xb[q0 * 3 + 1]; py[k].y = xb[q1 * 3 + 1];
        pz[k].x = xb[q0 * 3 + 2]; pz[k].y = xb[q1 * 3 + 2];
        d[k].x = 1e10f; d[k].y = 1e10f;
        sm.f.ptsx[q0 + 1] = px[k].x; sm.f.ptsx[q1 + 1] = px[k].y;
        sm.f.ptsy[q0 + 1] = py[k].x; sm.f.ptsy[q1 + 1] = py[k].y;
        sm.f.ptsz[q0 + 1] = pz[k].x; sm.f.ptsz[q1 + 1] = pz[k].y;
    }
    // ---- mean: bit-identical replication of the v1 1024-partial tree ----
    float sxA = 0.f, syA = 0.f, szA = 0.f;
    float sxB = 0.f, syB = 0.f, szB = 0.f;
    int uA = (t + 1023) & 1023;
    int uB = (t + 511) & 1023;
#pragma unroll
    for (int j = 0; j < 8; ++j) {
        int ia = uA + 1024 * j;
        int ib = uB + 1024 * j;
        sxA += xb[ia * 3 + 0]; syA += xb[ia * 3 + 1]; szA += xb[ia * 3 + 2];
        sxB += xb[ib * 3 + 0]; syB += xb[ib * 3 + 1]; szB += xb[ib * 3 + 2];
    }
#pragma unroll
    for (int off = 32; off; off >>= 1) {
        sxA += __shfl_xor(sxA, off, 64);
        syA += __shfl_xor(syA, off, 64);
        szA += __shfl_xor(szA, off, 64);
        sxB += __shfl_xor(sxB, off, 64);
        syB += __shfl_xor(syB, off, 64);
        szB += __shfl_xor(szB, off, 64);
    }
    if (lane == 0) {
        sm.f.ldsM[wv][0] = sxA; sm.f.ldsM[wv][1] = syA; sm.f.ldsM[wv][2] = szA;
        sm.f.ldsM[wv + 8][0] = sxB; sm.f.ldsM[wv + 8][1] = syB; sm.f.ldsM[wv + 8][2] = szB;
    }
    __syncthreads();
    if (t < 3) {
        float s = 0.f;
        for (int w = 0; w < 16; ++w) s += sm.f.ldsM[w][t];
        sm.f.meanv[t] = s * (1.f / 8192.f);
    }
    __syncthreads();
    float cx = sm.f.meanv[0], cy = sm.f.meanv[1], cz = sm.f.meanv[2];
    const float mmx = cx, mmy = cy, mmz = cz;  // mean point (pts idx 0), owned by t0
    float dm = 1e10f;
    if (t == 0) { sm.f.ptsx[0] = cx; sm.f.ptsy[0] = cy; sm.f.ptsz[0] = cz; }
    __syncthreads();

    for (int it = 0; it < 1024; ++it) {
        if (t == 0) {
            float* o = newxyz + ((size_t)b * 1024 + it) * 3;
            o[0] = cx; o[1] = cy; o[2] = cz;
        }
        f32x2 c0, c1, c2, vm2;
        c0.x = cx; c0.y = cx; c1.x = cy; c1.y = cy; c2.x = cz; c2.y = cz;
        vm2.x = -1e30f; vm2.y = -1e30f;
        {
#pragma clang fp contract(off)
            // plain -,*,+ with contraction off == __fsub_rn/__fmul_rn/__fadd_rn
            // ordering of v1..v4 (bit-exact); pairs lower to v_pk_add/mul_f32.
#pragma unroll
            for (int k = 0; k < 8; ++k) {
                f32x2 dx = px[k] - c0;
                f32x2 dy = py[k] - c1;
                f32x2 dz = pz[k] - c2;
                f32x2 dd = (dx * dx + dy * dy) + dz * dz;
                f32x2 nd = __builtin_elementwise_min(d[k], dd);
                d[k] = nd;
                vm2 = __builtin_elementwise_max(vm2, nd);
            }
        }
        float vmax = fmaxf(vm2.x, vm2.y);
        if (t == 0) {
            float dx = __fsub_rn(mmx, cx);
            float dy = __fsub_rn(mmy, cy);
            float dz = __fsub_rn(mmz, cz);
            float dd = __fadd_rn(__fadd_rn(__fmul_rn(dx, dx), __fmul_rn(dy, dy)), __fmul_rn(dz, dz));
            dm = fminf(dm, dd);
            vmax = fmaxf(vmax, dm);
        }
        float wm = wave_red_max_f32(vmax);
        float bmaxw = __int_as_float(__builtin_amdgcn_readlane(__float_as_int(wm), 63));
        // first-occurrence (= smallest pts index) among ties: independent cmps + min tree
        unsigned m2[8];
#pragma unroll
        for (int k = 0; k < 8; ++k) {
            unsigned i0 = (d[k].x == bmaxw) ? (unsigned)(t + 512 * (2 * k) + 1) : 0xFFFFFFFFu;
            unsigned i1 = (d[k].y == bmaxw) ? (unsigned)(t + 512 * (2 * k + 1) + 1) : 0xFFFFFFFFu;
            m2[k] = u32min(i0, i1);
        }
        unsigned n0 = u32min(m2[0], m2[1]), n1 = u32min(m2[2], m2[3]);
        unsigned n2 = u32min(m2[4], m2[5]), n3 = u32min(m2[6], m2[7]);
        unsigned mi = u32min(u32min(n0, n1), u32min(n2, n3));
        if (t == 0 && dm == bmaxw) mi = 0u;
        unsigned wmin = wave_red_min_u32(mi);
        unsigned miw = (unsigned)__builtin_amdgcn_readlane((int)wmin, 63);
        int par = it & 1;
        if (lane == 0)
            sm.f.sKey[par][wv] = ((unsigned long long)__float_as_uint(bmaxw) << 32) |
                                 (unsigned long long)(8192u - miw);
        __syncthreads();  // the ONLY barrier per iteration (parity-double-buffered slots)
        unsigned long long ka[8];
#pragma unroll
        for (int i = 0; i < 8; ++i) ka[i] = sm.f.sKey[par][i];  // same-address broadcasts
        unsigned long long p0 = u64max(ka[0], ka[1]), p1 = u64max(ka[2], ka[3]);
        unsigned long long p2 = u64max(ka[4], ka[5]), p3 = u64max(ka[6], ka[7]);
        unsigned long long kk = u64max(u64max(p0, p1), u64max(p2, p3));
        int far = 8192 - (int)(unsigned)(kk & 0xffffffffull);
        cx = sm.f.ptsx[far];  // uniform LDS broadcast
        cy = sm.f.ptsy[far];
        cz = sm.f.ptsz[far];
    }
}

// ---------------- ball query (unchanged) ---------------------------------------
__global__ void ball_query_kernel(const float* __restrict__ xyz, const float* __restrict__ newxyz,
                                  int* __restrict__ idxout, float r2, int K) {
    int wid = (blockIdx.x * blockDim.x + threadIdx.x) >> 6;
    int lane = threadIdx.x & 63;
    int b = wid >> 10;
    const float* q = newxyz + (size_t)wid * 3;
    float qx = q[0], qy = q[1], qz = q[2];
    const float* xb = xyz + (size_t)b * 8192 * 3;
    int* out = idxout + (size_t)wid * K;
    int count = 0;
    int first = 0;
    for (int base = 0; base < 8192 && count < K; base += 64) {
        int j = base + lane;
        float dx = __fsub_rn(xb[j * 3 + 0], qx);
        float dy = __fsub_rn(xb[j * 3 + 1], qy);
        float dz = __fsub_rn(xb[j * 3 + 2], qz);
        float d2 = __fadd_rn(__fadd_rn(__fmul_rn(dx, dx), __fmul_rn(dy, dy)), __fmul_rn(dz, dz));
        bool in = d2 < r2;
        unsigned long long m = __ballot(in);
        if (count == 0 && m) first = base + __ffsll((long long)m) - 1;
        if (in) {
            int pos = count + __popcll(m & ((1ull << lane) - 1ull));
            if (pos < K) out[pos] = j;
        }
        count += __popcll(m);
    }
    if (count < K) {
        int fillv = (count > 0) ? first : 0;
        for (int p = count + lane; p < K; p += 64) out[p] = fillv;
    }
}

// ---------------- MFMA GEMM (unchanged from v3/v4) ------------------------------
template <int Mp, int Kp, int IN_MODE, int OUT_MODE, int KSH>
__global__ __launch_bounds__(256) void gemm_mfma(
    const unsigned short* __restrict__ Wb, const unsigned short* __restrict__ Xin,
    const float* __restrict__ aff, const int* __restrict__ idx,
    const unsigned short* __restrict__ ftp, const float* __restrict__ newxyz,
    unsigned short* __restrict__ Yout, float* __restrict__ MX, float* __restrict__ MN,
    float* __restrict__ statS, float* __restrict__ statQ) {
    constexpr int MT = Mp / 64;
    constexpr int KS = Kp / 32;
    const int tid = threadIdx.x;
    const int w = tid >> 6;
    const int lane = tid & 63;
    const int n = lane & 15;
    const int quad = lane >> 4;
    const int rbase = w * (Mp / 4);
    const long col0 = (long)blockIdx.x * 64;

    short8 a[MT][KS];
#pragma unroll
    for (int mt = 0; mt < MT; ++mt)
#pragma unroll
        for (int ks = 0; ks < KS; ++ks)
            a[mt][ks] = *(const short8*)(Wb + (size_t)(rbase + mt * 16 + n) * Kp + ks * 32 + quad * 8);

    f32x4 acc[MT][4];
#pragma unroll
    for (int mt = 0; mt < MT; ++mt)
#pragma unroll
        for (int nt = 0; nt < 4; ++nt)
#pragma unroll
            for (int r = 0; r < 4; ++r) acc[mt][nt][r] = 0.f;

    long fbase[4];
    float qv0[4], qv1[4], qv2[4];
    if constexpr (IN_MODE == 0) {
        int bb = (int)(col0 >> (KSH + 10));
#pragma unroll
        for (int nt = 0; nt < 4; ++nt) {
            long col = col0 + nt * 16 + n;
            int j = idx[col];
            fbase[nt] = ((long)bb * 8192 + j) * 96;
            long sk = col >> KSH;
            qv0[nt] = newxyz[sk * 3 + 0];
            qv1[nt] = newxyz[sk * 3 + 1];
            qv2[nt] = newxyz[sk * 3 + 2];
        }
    }

#pragma unroll
    for (int ks = 0; ks < KS; ++ks) {
        float sc[8], sh[8];
        if constexpr (IN_MODE == 1) {
#pragma unroll
            for (int e = 0; e < 8; ++e) {
                sc[e] = aff[ks * 32 + quad * 8 + e];
                sh[e] = aff[Kp + ks * 32 + quad * 8 + e];
            }
        }
#pragma unroll
        for (int nt = 0; nt < 4; ++nt) {
            short8 bfr;
            if constexpr (IN_MODE == 0) {
                bfr = *(const short8*)(ftp + fbase[nt] + ks * 32 + quad * 8);
                if (ks == 0 && quad == 0) {
                    bfr[0] = (short)f2bf(bf2f((unsigned short)bfr[0]) - qv0[nt]);
                    bfr[1] = (short)f2bf(bf2f((unsigned short)bfr[1]) - qv1[nt]);
                    bfr[2] = (short)f2bf(bf2f((unsigned short)bfr[2]) - qv2[nt]);
                }
            } else {
                long col = col0 + nt * 16 + n;
                short8 raw = *(const short8*)(Xin + col * Kp + ks * 32 + quad * 8);
#pragma unroll
                for (int e = 0; e < 8; ++e) {
                    float xf = bf2f((unsigned short)raw[e]);
                    xf = fmaxf(fmaf(xf, sc[e], sh[e]), 0.f);
                    bfr[e] = (short)f2bf(xf);
                }
            }
#pragma unroll
            for (int mt = 0; mt < MT; ++mt)
                acc[mt][nt] = __builtin_amdgcn_mfma_f32_16x16x32_bf16(a[mt][ks], bfr, acc[mt][nt], 0, 0, 0);
        }
    }

    const int slot = (int)(blockIdx.x & 127);
#pragma unroll
    for (int mt = 0; mt < MT; ++mt)
#pragma unroll
        for (int r = 0; r < 4; ++r) {
            float s = 0.f, q = 0.f;
#pragma unroll
            for (int nt = 0; nt < 4; ++nt) {
                float v = acc[mt][nt][r];
                s += v;
                q = fmaf(v, v, q);
            }
#pragma unroll
            for (int off = 1; off < 16; off <<= 1) {
                s += __shfl_xor(s, off, 16);
                q += __shfl_xor(q, off, 16);
            }
            if (n == 0) {
                int ch = rbase + mt * 16 + quad * 4 + r;
                atomicAdd(statS + (size_t)ch * 128 + slot, s);
                atomicAdd(statQ + (size_t)ch * 128 + slot, q);
            }
        }

    if constexpr (OUT_MODE == 0) {
#pragma unroll
        for (int mt = 0; mt < MT; ++mt)
#pragma unroll
            for (int nt = 0; nt < 4; ++nt) {
                long col = col0 + nt * 16 + n;
                unsigned p0 = f2bf(acc[mt][nt][0]) | ((unsigned)f2bf(acc[mt][nt][1]) << 16);
                unsigned p1 = f2bf(acc[mt][nt][2]) | ((unsigned)f2bf(acc[mt][nt][3]) << 16);
                uint2 st; st.x = p0; st.y = p1;
                *(uint2*)(Yout + col * Mp + rbase + mt * 16 + quad * 4) = st;
            }
    } else {
#pragma unroll
        for (int mt = 0; mt < MT; ++mt)
#pragma unroll
            for (int r = 0; r < 4; ++r) {
                if constexpr (KSH == 6) {
                    float mx = acc[mt][0][r], mn = acc[mt][0][r];
#pragma unroll
                    for (int nt = 1; nt < 4; ++nt) {
                        mx = fmaxf(mx, acc[mt][nt][r]);
                        mn = fminf(mn, acc[mt][nt][r]);
                    }
#pragma unroll
                    for (int off = 1; off < 16; off <<= 1) {
                        mx = fmaxf(mx, __shfl_xor(mx, off, 16));
                        mn = fminf(mn, __shfl_xor(mn, off, 16));
                    }
                    if (n == 0) {
                        int ch = rbase + mt * 16 + quad * 4 + r;
                        long g = col0 >> 6;
                        MX[(long)ch * 8192 + g] = mx;
                        MN[(long)ch * 8192 + g] = mn;
                    }
                } else {
#pragma unroll
                    for (int gh = 0; gh < 2; ++gh) {
                        float mx = fmaxf(acc[mt][2 * gh][r], acc[mt][2 * gh + 1][r]);
                        float mn = fminf(acc[mt][2 * gh][r], acc[mt][2 * gh + 1][r]);
#pragma unroll
                        for (int off = 1; off < 16; off <<= 1) {
                            mx = fmaxf(mx, __shfl_xor(mx, off, 16));
                            mn = fminf(mn, __shfl_xor(mn, off, 16));
                        }
                        if (n == 0) {
                            int ch = rbase + mt * 16 + quad * 4 + r;
                            long g = (col0 >> 5) + gh;
                            MX[(long)ch * 8192 + g] = mx;
                            MN[(long)ch * 8192 + g] = mn;
                        }
                    }
                }
            }
    }
}

// ---------------- finalize BN constants ----------------------------------------
__global__ void finalize_kernel(const float* __restrict__ sS, const float* __restrict__ sQ,
                                const float* __restrict__ g, const float* __restrict__ b,
                                float* __restrict__ aff, int C, float invCount) {
    int c = threadIdx.x + blockIdx.x * blockDim.x;
    if (c >= C) return;
    float s = 0.f, q = 0.f;
    for (int k = 0; k < 128; ++k) { s += sS[c * 128 + k]; q += sQ[c * 128 + k]; }
    float mean = s * invCount;
    float var = fmaxf(q * invCount - mean * mean, 0.f);
    float sc = g[c] / sqrtf(var + 1e-5f);
    float sh = b[c] - mean * sc;
    aff[c] = sc;
    aff[C + c] = sh;
}

// ---------------- final output -------------------------------------------------
__global__ void final_out_kernel(const float* __restrict__ MX, const float* __restrict__ MN,
                                 const float* __restrict__ aff, float* __restrict__ out1,
                                 int Cout, int cOff) {
    long i = (long)blockIdx.x * 256 + threadIdx.x;
    int c = (int)(i >> 13);
    int gidx = (int)(i & 8191);
    int b = gidx >> 10, s = gidx & 1023;
    float sc = aff[c], sh = aff[Cout + c];
    float v = fmaxf(fmaxf(sc * MX[i] + sh, sc * MN[i] + sh), 0.f);
    out1[((long)b * 384 + cOff + c) * 1024 + s] = v;
}

// ---------------- host ---------------------------------------------------------
extern "C" void kernel_launch(void* const* d_in, const int* in_sizes, int n_in,
                              void* d_out, int out_size, void* d_ws, size_t ws_size,
                              hipStream_t stream) {
    const float* xyz = (const float*)d_in[0];
    const float* feat = (const float*)d_in[1];
    const float *W[6], *G[6], *Bi[6];
    for (int l = 0; l < 6; ++l) {
        W[l] = (const float*)d_in[2 + l * 3];
        G[l] = (const float*)d_in[3 + l * 3];
        Bi[l] = (const float*)d_in[4 + l * 3];
    }
    char* ws = (char*)d_ws;
    float* out0 = (float*)d_out;
    float* out1 = (float*)d_out + 24576;

    unsigned short* wb = (unsigned short*)(ws + OFF_WBF);
    float* stats = (float*)(ws + OFF_STATS);
    float* affine = (float*)(ws + OFF_AFF);
    int* idx0 = (int*)(ws + OFF_IDX0);
    int* idx1 = (int*)(ws + OFF_IDX1);
    float* mx = (float*)(ws + OFF_MX);
    float* mn = (float*)(ws + OFF_MN);
    unsigned short* y0 = (unsigned short*)(ws + OFF_Y0);
    unsigned short* y1 = (unsigned short*)(ws + OFF_Y1);
    unsigned short* ftp = (unsigned short*)(ws + OFF_FEATT);

    hipMemsetAsync(stats, 0, STATS_BYTES, stream);
    fused_pre<<<1160, 512, 0, stream>>>(xyz, feat, out0, ftp, W[0], W[1], W[2], W[3], W[4],
                                        W[5], wb);

    const int wOff[6] = {0, 6144, 10240, 18432, 24576, 32768};
    int stOff[6], afOff[6];
    {
        const int Cs[6] = {64, 64, 128, 64, 128, 256};
        int so = 0, ao = 0;
        for (int l = 0; l < 6; ++l) {
            stOff[l] = so; so += Cs[l] * 256;
            afOff[l] = ao; ao += Cs[l] * 2;
        }
    }

    for (int br = 0; br < 2; ++br) {
        const int K = br ? 64 : 32;
        const float radius = br ? 0.8f : 0.4f;
        const long NCOL = 8L * 1024 * K;
        int* idx = br ? idx1 : idx0;
        const int l0 = br * 3, l1 = br * 3 + 1, l2 = br * 3 + 2;
        const int M2 = br ? 256 : 128;
        const float invCount = 1.f / (float)NCOL;
        const int nblk = (int)(NCOL / 64);

        ball_query_kernel<<<2048, 256, 0, stream>>>(xyz, out0, idx, radius * radius, K);

        if (br == 0) {
            gemm_mfma<64, 96, 0, 0, 5><<<nblk, 256, 0, stream>>>(
                wb + wOff[l0], nullptr, nullptr, idx, ftp, out0, y0, nullptr, nullptr,
                stats + stOff[l0], stats + stOff[l0] + 64 * 128);
            finalize_kernel<<<1, 256, 0, stream>>>(stats + stOff[l0], stats + stOff[l0] + 64 * 128,
                                                   G[l0], Bi[l0], affine + afOff[l0], 64, invCount);
            gemm_mfma<64, 64, 1, 0, 5><<<nblk, 256, 0, stream>>>(
                wb + wOff[l1], y0, affine + afOff[l0], nullptr, nullptr, nullptr, y1, nullptr,
                nullptr, stats + stOff[l1], stats + stOff[l1] + 64 * 128);
            finalize_kernel<<<1, 256, 0, stream>>>(stats + stOff[l1], stats + stOff[l1] + 64 * 128,
                                                   G[l1], Bi[l1], affine + afOff[l1], 64, invCount);
            gemm_mfma<128, 64, 1, 1, 5><<<nblk, 256, 0, stream>>>(
                wb + wOff[l2], y1, affine + afOff[l1], nullptr, nullptr, nullptr, nullptr, mx, mn,
                stats + stOff[l2], stats + stOff[l2] + 128 * 128);
            finalize_kernel<<<1, 256, 0, stream>>>(stats + stOff[l2], stats + stOff[l2] + 128 * 128,
                                                   G[l2], Bi[l2], affine + afOff[l2], 128, invCount);
        } else {
            gemm_mfma<64, 96, 0, 0, 6><<<nblk, 256, 0, stream>>>(
                wb + wOff[l0], nullptr, nullptr, idx, ftp, out0, y0, nullptr, nullptr,
                stats + stOff[l0], stats + stOff[l0] + 64 * 128);
            finalize_kernel<<<1, 256, 0, stream>>>(stats + stOff[l0], stats + stOff[l0] + 64 * 128,
                                                   G[l0], Bi[l0], affine + afOff[l0], 64, invCount);
            gemm_mfma<128, 64, 1, 0, 6><<<nblk, 256, 0, stream>>>(
                wb + wOff[l1], y0, affine + afOff[l0], nullptr, nullptr, nullptr, y1, nullptr,
                nullptr, stats + stOff[l1], stats + stOff[l1] + 128 * 128);
            finalize_kernel<<<1, 256, 0, stream>>>(stats + stOff[l1], stats + stOff[l1] + 128 * 128,
                                                   G[l1], Bi[l1], affine + afOff[l1], 128, invCount);
            gemm_mfma<256, 128, 1, 1, 6><<<nblk, 256, 0, stream>>>(
                wb + wOff[l2], y1, affine + afOff[l1], nullptr, nullptr, nullptr, nullptr, mx, mn,
                stats + stOff[l2], stats + stOff[l2] + 256 * 128);
            finalize_kernel<<<1, 256, 0, stream>>>(stats + stOff[l2], stats + stOff[l2] + 256 * 128,
                                                   G[l2], Bi[l2], affine + afOff[l2], 256, invCount);
        }

        final_out_kernel<<<(M2 * 8192) / 256, 256, 0, stream>>>(mx, mn, affine + afOff[l2], out1,
                                                                M2, br ? 128 : 0);
    }
}